// Round 1
// baseline (358.427 us; speedup 1.0000x reference)
//
#include <hip/hip_runtime.h>
#include <hip/hip_bf16.h>
#include <math.h>

// ---------------------------------------------------------------------------
// MultiLayerGAT: 3x GATConv (PyG-style, self-loops added) + log_softmax.
// N=10000 nodes, E=320000 edges, layers: 128->8x32 (elu) -> 256->8x32 (elu)
// -> 256->40 (H=1, mean==identity) -> log_softmax.
//
// Strategy:
//   - Build CSR by dst once (count/scan/scatter). Self loop (d,d) handled
//     implicitly in the aggregation kernels (reference appends it).
//   - Per layer: GEMM (xp = h @ W), attention logits al_s/al_d per (node,head),
//     then one wave per dst node does segment max / exp-sum / weighted gather
//     sequentially over its in-edges (no atomics, fp4-vectorized gathers).
//   - Layer 3 fuses bias + log_softmax in the aggregation epilogue.
// ---------------------------------------------------------------------------

#define DEV_INLINE __device__ __forceinline__

DEV_INLINE float leaky02(float x) { return x > 0.f ? x : 0.2f * x; }
DEV_INLINE float elu1(float x) { return x > 0.f ? x : expm1f(x); }

// ---------------- CSR build ----------------

__global__ void count_deg_kernel(const int* __restrict__ dst, int* __restrict__ deg, int e) {
    int i = blockIdx.x * blockDim.x + threadIdx.x;
    if (i < e) atomicAdd(&deg[dst[i]], 1);
}

// Single-block scan: reads deg (may alias cursor), writes row_start[0..n] and cursor[0..n-1].
__global__ __launch_bounds__(1024) void scan_deg_kernel(const int* __restrict__ deg,
                                                        int* __restrict__ row_start,
                                                        int* __restrict__ cursor, int n) {
    __shared__ int sums[1024];
    const int t = threadIdx.x;
    constexpr int ITEMS = 16;               // 1024*16 = 16384 >= n
    const int base = t * ITEMS;
    int local[ITEMS];
    int run = 0;
#pragma unroll
    for (int i = 0; i < ITEMS; ++i) {
        int idx = base + i;
        int v = (idx < n) ? deg[idx] : 0;
        local[i] = run;
        run += v;
    }
    sums[t] = run;
    __syncthreads();
    for (int off = 1; off < 1024; off <<= 1) {
        int v = (t >= off) ? sums[t - off] : 0;
        __syncthreads();
        sums[t] += v;
        __syncthreads();
    }
    int prefix = (t == 0) ? 0 : sums[t - 1];
#pragma unroll
    for (int i = 0; i < ITEMS; ++i) {
        int idx = base + i;
        if (idx < n) {
            int v = prefix + local[i];
            row_start[idx] = v;
            cursor[idx] = v;
        }
    }
    if (t == 1023) row_start[n] = sums[1023];
}

__global__ void scatter_csr_kernel(const int* __restrict__ src, const int* __restrict__ dst,
                                   int* __restrict__ cursor, int* __restrict__ csr_src, int e) {
    int i = blockIdx.x * blockDim.x + threadIdx.x;
    if (i < e) {
        int p = atomicAdd(&cursor[dst[i]], 1);
        csr_src[p] = src[i];
    }
}

// ---------------- GEMM: C[M,N] = A[M,K] @ B[K,N], f32, K % 16 == 0 ----------------

__global__ __launch_bounds__(256) void gemm_f32_64x64(const float* __restrict__ A,
                                                      const float* __restrict__ B,
                                                      float* __restrict__ C,
                                                      int M, int N, int K) {
    constexpr int BM = 64, BN = 64, BK = 16;
    __shared__ float As[BK][BM];
    __shared__ float Bs[BK][BN];
    const int tid = threadIdx.x;
    const int tr = tid >> 4;   // 0..15
    const int tc = tid & 15;   // 0..15
    const int row0 = blockIdx.y * BM;
    const int col0 = blockIdx.x * BN;
    float acc[4][4] = {};
    for (int k0 = 0; k0 < K; k0 += BK) {
#pragma unroll
        for (int j = 0; j < 4; ++j) {
            int idx = tid + j * 256;
            int m = idx >> 4;
            int k = idx & 15;
            int gm = row0 + m;
            As[k][m] = (gm < M) ? A[(size_t)gm * K + k0 + k] : 0.f;
        }
#pragma unroll
        for (int j = 0; j < 4; ++j) {
            int idx = tid + j * 256;
            int k = idx >> 6;
            int nn = idx & 63;
            int gn = col0 + nn;
            Bs[k][nn] = (gn < N) ? B[(size_t)(k0 + k) * N + gn] : 0.f;
        }
        __syncthreads();
#pragma unroll
        for (int k = 0; k < BK; ++k) {
            float a[4], b[4];
#pragma unroll
            for (int i = 0; i < 4; ++i) a[i] = As[k][tr * 4 + i];
#pragma unroll
            for (int j = 0; j < 4; ++j) b[j] = Bs[k][tc * 4 + j];
#pragma unroll
            for (int i = 0; i < 4; ++i)
#pragma unroll
                for (int j = 0; j < 4; ++j) acc[i][j] += a[i] * b[j];
        }
        __syncthreads();
    }
#pragma unroll
    for (int i = 0; i < 4; ++i) {
        int gm = row0 + tr * 4 + i;
        if (gm >= M) continue;
#pragma unroll
        for (int j = 0; j < 4; ++j) {
            int gn = col0 + tc * 4 + j;
            if (gn < N) C[(size_t)gm * N + gn] = acc[i][j];
        }
    }
}

// ---------------- attention logits, H=8, C=32 (HC=256) ----------------
// One wave per node; lane l handles channels 4l..4l+3; head = l>>3.

__global__ __launch_bounds__(256) void al_heads_kernel(const float* __restrict__ xp,
                                                       const float* __restrict__ a_src,
                                                       const float* __restrict__ a_dst,
                                                       float* __restrict__ als,
                                                       float* __restrict__ ald, int n) {
    int node = (blockIdx.x * blockDim.x + threadIdx.x) >> 6;
    int lane = threadIdx.x & 63;
    if (node >= n) return;
    float4 xv = *(const float4*)(xp + (size_t)node * 256 + lane * 4);
    float4 as4 = *(const float4*)(a_src + lane * 4);
    float4 ad4 = *(const float4*)(a_dst + lane * 4);
    float ps = xv.x * as4.x + xv.y * as4.y + xv.z * as4.z + xv.w * as4.w;
    float pd = xv.x * ad4.x + xv.y * ad4.y + xv.z * ad4.z + xv.w * ad4.w;
#pragma unroll
    for (int off = 1; off < 8; off <<= 1) {
        ps += __shfl_xor(ps, off);
        pd += __shfl_xor(pd, off);
    }
    if ((lane & 7) == 0) {
        als[node * 8 + (lane >> 3)] = ps;
        ald[node * 8 + (lane >> 3)] = pd;
    }
}

// ---------------- aggregation, layers 1-2 (H=8, C=32) + bias + ELU ----------------

__global__ __launch_bounds__(256) void aggregate_h8_kernel(const float* __restrict__ xp,
                                                           const float* __restrict__ als,
                                                           const float* __restrict__ ald,
                                                           const int* __restrict__ row_start,
                                                           const int* __restrict__ csr_src,
                                                           const float* __restrict__ bias,
                                                           float* __restrict__ out, int n) {
    int node = (blockIdx.x * blockDim.x + threadIdx.x) >> 6;
    int lane = threadIdx.x & 63;
    if (node >= n) return;
    const int head = lane >> 3;
    const int rs = row_start[node], re = row_start[node + 1];
    const float ad = ald[node * 8 + head];
    const float e_self = leaky02(als[node * 8 + head] + ad);

    // pass A: segment max (self loop included)
    float m = e_self;
    for (int i = rs; i < re; ++i) {
        int s = csr_src[i];
        m = fmaxf(m, leaky02(als[s * 8 + head] + ad));
    }

    // pass B: exp-sum + weighted gather
    float ee = __expf(e_self - m);
    float ssum = ee;
    float4 xv = *(const float4*)(xp + (size_t)node * 256 + lane * 4);
    float4 acc;
    acc.x = ee * xv.x; acc.y = ee * xv.y; acc.z = ee * xv.z; acc.w = ee * xv.w;
    for (int i = rs; i < re; ++i) {
        int s = csr_src[i];
        float e2 = __expf(leaky02(als[s * 8 + head] + ad) - m);
        ssum += e2;
        float4 v = *(const float4*)(xp + (size_t)s * 256 + lane * 4);
        acc.x += e2 * v.x; acc.y += e2 * v.y; acc.z += e2 * v.z; acc.w += e2 * v.w;
    }
    float inv = 1.f / (ssum + 1e-16f);
    float4 b4 = *(const float4*)(bias + lane * 4);
    float4 o;
    o.x = elu1(acc.x * inv + b4.x);
    o.y = elu1(acc.y * inv + b4.y);
    o.z = elu1(acc.z * inv + b4.z);
    o.w = elu1(acc.w * inv + b4.w);
    *(float4*)(out + (size_t)node * 256 + lane * 4) = o;
}

// ---------------- attention logits layer 3 (H=1, C=40) ----------------

__global__ void al_out_kernel(const float* __restrict__ xp, const float* __restrict__ a_src,
                              const float* __restrict__ a_dst, float* __restrict__ als,
                              float* __restrict__ ald, int n) {
    int i = blockIdx.x * blockDim.x + threadIdx.x;
    if (i >= n) return;
    float s = 0.f, d = 0.f;
#pragma unroll 8
    for (int c = 0; c < 40; ++c) {
        float v = xp[(size_t)i * 40 + c];
        s += v * a_src[c];
        d += v * a_dst[c];
    }
    als[i] = s;
    ald[i] = d;
}

// ---------------- aggregation layer 3 (H=1, C=40) + bias + log_softmax ----------------

__global__ __launch_bounds__(256) void aggregate_out_kernel(const float* __restrict__ xp,
                                                            const float* __restrict__ als,
                                                            const float* __restrict__ ald,
                                                            const int* __restrict__ row_start,
                                                            const int* __restrict__ csr_src,
                                                            const float* __restrict__ bias,
                                                            float* __restrict__ out, int n) {
    int node = (blockIdx.x * blockDim.x + threadIdx.x) >> 6;
    int lane = threadIdx.x & 63;
    if (node >= n) return;
    const int rs = row_start[node], re = row_start[node + 1];
    const float ad = ald[node];
    const float e_self = leaky02(als[node] + ad);

    float m = e_self;
    for (int i = rs; i < re; ++i) {
        int s = csr_src[i];
        m = fmaxf(m, leaky02(als[s] + ad));
    }

    float ee = __expf(e_self - m);
    float ssum = ee;
    float acc = (lane < 40) ? ee * xp[(size_t)node * 40 + lane] : 0.f;
    for (int i = rs; i < re; ++i) {
        int s = csr_src[i];
        float e2 = __expf(leaky02(als[s] + ad) - m);
        ssum += e2;
        float v = (lane < 40) ? xp[(size_t)s * 40 + lane] : 0.f;
        acc += e2 * v;
    }
    float inv = 1.f / (ssum + 1e-16f);
    float o = (lane < 40) ? (acc * inv + bias[lane]) : -INFINITY;

    // log_softmax over the 40 channels (wave-wide reduce)
    float mx = o;
#pragma unroll
    for (int off = 32; off >= 1; off >>= 1) mx = fmaxf(mx, __shfl_xor(mx, off));
    float ex = (lane < 40) ? __expf(o - mx) : 0.f;
    float se = ex;
#pragma unroll
    for (int off = 32; off >= 1; off >>= 1) se += __shfl_xor(se, off);
    float lse = mx + __logf(se);
    if (lane < 40) out[(size_t)node * 40 + lane] = o - lse;
}

// ---------------------------------------------------------------------------

extern "C" void kernel_launch(void* const* d_in, const int* in_sizes, int n_in,
                              void* d_out, int out_size, void* d_ws, size_t ws_size,
                              hipStream_t stream) {
    const float* x      = (const float*)d_in[0];
    const int*   edge   = (const int*)d_in[1];
    const float* W1     = (const float*)d_in[2];
    const float* a_src1 = (const float*)d_in[3];
    const float* a_dst1 = (const float*)d_in[4];
    const float* b1     = (const float*)d_in[5];
    const float* W2     = (const float*)d_in[6];
    const float* a_src2 = (const float*)d_in[7];
    const float* a_dst2 = (const float*)d_in[8];
    const float* b2     = (const float*)d_in[9];
    const float* W3     = (const float*)d_in[10];
    const float* a_src3 = (const float*)d_in[11];
    const float* a_dst3 = (const float*)d_in[12];
    const float* b3     = (const float*)d_in[13];
    float* out = (float*)d_out;

    const int n = in_sizes[0] / 128;   // 10000
    const int e = in_sizes[1] / 2;     // 320000

    char* ws = (char*)d_ws;
    size_t off = 0;
    auto alloc = [&](size_t bytes) -> void* {
        void* p = ws + off;
        off += (bytes + 255) & ~(size_t)255;
        return p;
    };
    float* xp        = (float*)alloc((size_t)n * 256 * 4);
    float* h         = (float*)alloc((size_t)n * 256 * 4);
    float* als       = (float*)alloc((size_t)n * 8 * 4);
    float* ald       = (float*)alloc((size_t)n * 8 * 4);
    int*   row_start = (int*)alloc((size_t)(n + 1) * 4);
    int*   cursor    = (int*)alloc((size_t)n * 4);
    int*   csr_src   = (int*)alloc((size_t)e * 4);
    (void)ws_size;

    const int* srcs = edge;
    const int* dsts = edge + e;

    // --- CSR build (every call: ws is not preserved/zeroed between replays) ---
    hipMemsetAsync(cursor, 0, (size_t)n * 4, stream);
    count_deg_kernel<<<(e + 255) / 256, 256, 0, stream>>>(dsts, cursor, e);
    scan_deg_kernel<<<1, 1024, 0, stream>>>(cursor, row_start, cursor, n);
    scatter_csr_kernel<<<(e + 255) / 256, 256, 0, stream>>>(srcs, dsts, cursor, csr_src, e);

    const int waves_grid = (n * 64 + 255) / 256;

    // --- Layer 1: 128 -> 8x32, ELU ---
    gemm_f32_64x64<<<dim3((256 + 63) / 64, (n + 63) / 64), 256, 0, stream>>>(x, W1, xp, n, 256, 128);
    al_heads_kernel<<<waves_grid, 256, 0, stream>>>(xp, a_src1, a_dst1, als, ald, n);
    aggregate_h8_kernel<<<waves_grid, 256, 0, stream>>>(xp, als, ald, row_start, csr_src, b1, h, n);

    // --- Layer 2: 256 -> 8x32, ELU ---
    gemm_f32_64x64<<<dim3((256 + 63) / 64, (n + 63) / 64), 256, 0, stream>>>(h, W2, xp, n, 256, 256);
    al_heads_kernel<<<waves_grid, 256, 0, stream>>>(xp, a_src2, a_dst2, als, ald, n);
    aggregate_h8_kernel<<<waves_grid, 256, 0, stream>>>(xp, als, ald, row_start, csr_src, b2, h, n);

    // --- Layer 3: 256 -> 40, H=1, + log_softmax ---
    gemm_f32_64x64<<<dim3(1, (n + 63) / 64), 256, 0, stream>>>(h, W3, xp, n, 40, 256);
    al_out_kernel<<<(n + 255) / 256, 256, 0, stream>>>(xp, a_src3, a_dst3, als, ald, n);
    aggregate_out_kernel<<<waves_grid, 256, 0, stream>>>(xp, als, ald, row_start, csr_src, b3, out, n);
}

// Round 2
// 259.749 us; speedup vs baseline: 1.3799x; 1.3799x over previous
//
#include <hip/hip_runtime.h>
#include <hip/hip_bf16.h>
#include <math.h>

// ---------------------------------------------------------------------------
// MultiLayerGAT: 3x GATConv (PyG-style, self-loops added) + log_softmax.
// N=10000 nodes, E=320000 edges, layers: 128->8x32 (elu) -> 256->8x32 (elu)
// -> 256->40 (H=1, mean==identity) -> log_softmax.
//
// R1: aggregation kernels rewritten single-pass (shift by self-loop logit
// instead of segment max -- mathematically identical softmax), with batched
// coalesced edge-index loads + 4x unrolled independent gathers for MLP.
// ---------------------------------------------------------------------------

#define DEV_INLINE __device__ __forceinline__

DEV_INLINE float leaky02(float x) { return x > 0.f ? x : 0.2f * x; }
DEV_INLINE float elu1(float x) { return x > 0.f ? x : expm1f(x); }

// ---------------- CSR build ----------------

__global__ void count_deg_kernel(const int* __restrict__ dst, int* __restrict__ deg, int e) {
    int i = blockIdx.x * blockDim.x + threadIdx.x;
    if (i < e) atomicAdd(&deg[dst[i]], 1);
}

// Single-block scan: reads deg (may alias cursor), writes row_start[0..n] and cursor[0..n-1].
__global__ __launch_bounds__(1024) void scan_deg_kernel(const int* __restrict__ deg,
                                                        int* __restrict__ row_start,
                                                        int* __restrict__ cursor, int n) {
    __shared__ int sums[1024];
    const int t = threadIdx.x;
    constexpr int ITEMS = 16;               // 1024*16 = 16384 >= n
    const int base = t * ITEMS;
    int local[ITEMS];
    int run = 0;
#pragma unroll
    for (int i = 0; i < ITEMS; ++i) {
        int idx = base + i;
        int v = (idx < n) ? deg[idx] : 0;
        local[i] = run;
        run += v;
    }
    sums[t] = run;
    __syncthreads();
    for (int off = 1; off < 1024; off <<= 1) {
        int v = (t >= off) ? sums[t - off] : 0;
        __syncthreads();
        sums[t] += v;
        __syncthreads();
    }
    int prefix = (t == 0) ? 0 : sums[t - 1];
#pragma unroll
    for (int i = 0; i < ITEMS; ++i) {
        int idx = base + i;
        if (idx < n) {
            int v = prefix + local[i];
            row_start[idx] = v;
            cursor[idx] = v;
        }
    }
    if (t == 1023) row_start[n] = sums[1023];
}

__global__ void scatter_csr_kernel(const int* __restrict__ src, const int* __restrict__ dst,
                                   int* __restrict__ cursor, int* __restrict__ csr_src, int e) {
    int i = blockIdx.x * blockDim.x + threadIdx.x;
    if (i < e) {
        int p = atomicAdd(&cursor[dst[i]], 1);
        csr_src[p] = src[i];
    }
}

// ---------------- GEMM: C[M,N] = A[M,K] @ B[K,N], f32, K % 16 == 0 ----------------

__global__ __launch_bounds__(256) void gemm_f32_64x64(const float* __restrict__ A,
                                                      const float* __restrict__ B,
                                                      float* __restrict__ C,
                                                      int M, int N, int K) {
    constexpr int BM = 64, BN = 64, BK = 16;
    __shared__ float As[BK][BM];
    __shared__ float Bs[BK][BN];
    const int tid = threadIdx.x;
    const int tr = tid >> 4;   // 0..15
    const int tc = tid & 15;   // 0..15
    const int row0 = blockIdx.y * BM;
    const int col0 = blockIdx.x * BN;
    float acc[4][4] = {};
    for (int k0 = 0; k0 < K; k0 += BK) {
#pragma unroll
        for (int j = 0; j < 4; ++j) {
            int idx = tid + j * 256;
            int m = idx >> 4;
            int k = idx & 15;
            int gm = row0 + m;
            As[k][m] = (gm < M) ? A[(size_t)gm * K + k0 + k] : 0.f;
        }
#pragma unroll
        for (int j = 0; j < 4; ++j) {
            int idx = tid + j * 256;
            int k = idx >> 6;
            int nn = idx & 63;
            int gn = col0 + nn;
            Bs[k][nn] = (gn < N) ? B[(size_t)(k0 + k) * N + gn] : 0.f;
        }
        __syncthreads();
#pragma unroll
        for (int k = 0; k < BK; ++k) {
            float a[4], b[4];
#pragma unroll
            for (int i = 0; i < 4; ++i) a[i] = As[k][tr * 4 + i];
#pragma unroll
            for (int j = 0; j < 4; ++j) b[j] = Bs[k][tc * 4 + j];
#pragma unroll
            for (int i = 0; i < 4; ++i)
#pragma unroll
                for (int j = 0; j < 4; ++j) acc[i][j] += a[i] * b[j];
        }
        __syncthreads();
    }
#pragma unroll
    for (int i = 0; i < 4; ++i) {
        int gm = row0 + tr * 4 + i;
        if (gm >= M) continue;
#pragma unroll
        for (int j = 0; j < 4; ++j) {
            int gn = col0 + tc * 4 + j;
            if (gn < N) C[(size_t)gm * N + gn] = acc[i][j];
        }
    }
}

// ---------------- attention logits, H=8, C=32 (HC=256) ----------------
// One wave per node; lane l handles channels 4l..4l+3; head = l>>3.

__global__ __launch_bounds__(256) void al_heads_kernel(const float* __restrict__ xp,
                                                       const float* __restrict__ a_src,
                                                       const float* __restrict__ a_dst,
                                                       float* __restrict__ als,
                                                       float* __restrict__ ald, int n) {
    int node = (blockIdx.x * blockDim.x + threadIdx.x) >> 6;
    int lane = threadIdx.x & 63;
    if (node >= n) return;
    float4 xv = *(const float4*)(xp + (size_t)node * 256 + lane * 4);
    float4 as4 = *(const float4*)(a_src + lane * 4);
    float4 ad4 = *(const float4*)(a_dst + lane * 4);
    float ps = xv.x * as4.x + xv.y * as4.y + xv.z * as4.z + xv.w * as4.w;
    float pd = xv.x * ad4.x + xv.y * ad4.y + xv.z * ad4.z + xv.w * ad4.w;
#pragma unroll
    for (int off = 1; off < 8; off <<= 1) {
        ps += __shfl_xor(ps, off);
        pd += __shfl_xor(pd, off);
    }
    if ((lane & 7) == 0) {
        als[node * 8 + (lane >> 3)] = ps;
        ald[node * 8 + (lane >> 3)] = pd;
    }
}

// ---------------- aggregation, layers 1-2 (H=8, C=32) + bias + ELU ----------------
// Single pass: softmax shifted by self-loop logit (exact same alpha).
// Edge indices batch-loaded coalesced (64/wave), 4x unrolled gathers.

__global__ __launch_bounds__(256) void aggregate_h8_kernel(const float* __restrict__ xp,
                                                           const float* __restrict__ als,
                                                           const float* __restrict__ ald,
                                                           const int* __restrict__ row_start,
                                                           const int* __restrict__ csr_src,
                                                           const float* __restrict__ bias,
                                                           float* __restrict__ out, int n) {
    int node = (blockIdx.x * blockDim.x + threadIdx.x) >> 6;
    int lane = threadIdx.x & 63;
    if (node >= n) return;
    const int head = lane >> 3;
    const int rs = row_start[node], re = row_start[node + 1];
    const float ad = ald[node * 8 + head];
    const float m = leaky02(als[node * 8 + head] + ad);   // shift = self-loop logit

    float ssum = 1.0f;                                    // exp(e_self - m) == 1
    float4 acc = *(const float4*)(xp + (size_t)node * 256 + lane * 4);

    for (int base = rs; base < re; base += 64) {
        const int cnt = (re - base < 64) ? (re - base) : 64;
        int myi = (lane < cnt) ? csr_src[base + lane] : 0;

        int j = 0;
        for (; j + 4 <= cnt; j += 4) {
            int s0 = __shfl(myi, j);
            int s1 = __shfl(myi, j + 1);
            int s2 = __shfl(myi, j + 2);
            int s3 = __shfl(myi, j + 3);
            float a0 = als[s0 * 8 + head];
            float a1 = als[s1 * 8 + head];
            float a2 = als[s2 * 8 + head];
            float a3 = als[s3 * 8 + head];
            float4 v0 = *(const float4*)(xp + (size_t)s0 * 256 + lane * 4);
            float4 v1 = *(const float4*)(xp + (size_t)s1 * 256 + lane * 4);
            float4 v2 = *(const float4*)(xp + (size_t)s2 * 256 + lane * 4);
            float4 v3 = *(const float4*)(xp + (size_t)s3 * 256 + lane * 4);
            float p0 = __expf(leaky02(a0 + ad) - m);
            float p1 = __expf(leaky02(a1 + ad) - m);
            float p2 = __expf(leaky02(a2 + ad) - m);
            float p3 = __expf(leaky02(a3 + ad) - m);
            ssum += (p0 + p1) + (p2 + p3);
            acc.x += (p0 * v0.x + p1 * v1.x) + (p2 * v2.x + p3 * v3.x);
            acc.y += (p0 * v0.y + p1 * v1.y) + (p2 * v2.y + p3 * v3.y);
            acc.z += (p0 * v0.z + p1 * v1.z) + (p2 * v2.z + p3 * v3.z);
            acc.w += (p0 * v0.w + p1 * v1.w) + (p2 * v2.w + p3 * v3.w);
        }
        for (; j < cnt; ++j) {
            int s0 = __shfl(myi, j);
            float a0 = als[s0 * 8 + head];
            float4 v0 = *(const float4*)(xp + (size_t)s0 * 256 + lane * 4);
            float p0 = __expf(leaky02(a0 + ad) - m);
            ssum += p0;
            acc.x += p0 * v0.x;
            acc.y += p0 * v0.y;
            acc.z += p0 * v0.z;
            acc.w += p0 * v0.w;
        }
    }

    float inv = 1.f / ssum;
    float4 b4 = *(const float4*)(bias + lane * 4);
    float4 o;
    o.x = elu1(acc.x * inv + b4.x);
    o.y = elu1(acc.y * inv + b4.y);
    o.z = elu1(acc.z * inv + b4.z);
    o.w = elu1(acc.w * inv + b4.w);
    *(float4*)(out + (size_t)node * 256 + lane * 4) = o;
}

// ---------------- attention logits layer 3 (H=1, C=40) ----------------

__global__ void al_out_kernel(const float* __restrict__ xp, const float* __restrict__ a_src,
                              const float* __restrict__ a_dst, float* __restrict__ als,
                              float* __restrict__ ald, int n) {
    int i = blockIdx.x * blockDim.x + threadIdx.x;
    if (i >= n) return;
    float s = 0.f, d = 0.f;
#pragma unroll 8
    for (int c = 0; c < 40; ++c) {
        float v = xp[(size_t)i * 40 + c];
        s += v * a_src[c];
        d += v * a_dst[c];
    }
    als[i] = s;
    ald[i] = d;
}

// ---------------- aggregation layer 3 (H=1, C=40) + bias + log_softmax ----------------

__global__ __launch_bounds__(256) void aggregate_out_kernel(const float* __restrict__ xp,
                                                            const float* __restrict__ als,
                                                            const float* __restrict__ ald,
                                                            const int* __restrict__ row_start,
                                                            const int* __restrict__ csr_src,
                                                            const float* __restrict__ bias,
                                                            float* __restrict__ out, int n) {
    int node = (blockIdx.x * blockDim.x + threadIdx.x) >> 6;
    int lane = threadIdx.x & 63;
    if (node >= n) return;
    const int rs = row_start[node], re = row_start[node + 1];
    const float ad = ald[node];
    const float m = leaky02(als[node] + ad);              // shift = self-loop logit

    float ssum = 1.0f;
    float acc = (lane < 40) ? xp[(size_t)node * 40 + lane] : 0.f;

    for (int base = rs; base < re; base += 64) {
        const int cnt = (re - base < 64) ? (re - base) : 64;
        int myi = (lane < cnt) ? csr_src[base + lane] : 0;

        int j = 0;
        for (; j + 4 <= cnt; j += 4) {
            int s0 = __shfl(myi, j);
            int s1 = __shfl(myi, j + 1);
            int s2 = __shfl(myi, j + 2);
            int s3 = __shfl(myi, j + 3);
            float a0 = als[s0];
            float a1 = als[s1];
            float a2 = als[s2];
            float a3 = als[s3];
            float v0 = (lane < 40) ? xp[(size_t)s0 * 40 + lane] : 0.f;
            float v1 = (lane < 40) ? xp[(size_t)s1 * 40 + lane] : 0.f;
            float v2 = (lane < 40) ? xp[(size_t)s2 * 40 + lane] : 0.f;
            float v3 = (lane < 40) ? xp[(size_t)s3 * 40 + lane] : 0.f;
            float p0 = __expf(leaky02(a0 + ad) - m);
            float p1 = __expf(leaky02(a1 + ad) - m);
            float p2 = __expf(leaky02(a2 + ad) - m);
            float p3 = __expf(leaky02(a3 + ad) - m);
            ssum += (p0 + p1) + (p2 + p3);
            acc += (p0 * v0 + p1 * v1) + (p2 * v2 + p3 * v3);
        }
        for (; j < cnt; ++j) {
            int s0 = __shfl(myi, j);
            float a0 = als[s0];
            float v0 = (lane < 40) ? xp[(size_t)s0 * 40 + lane] : 0.f;
            float p0 = __expf(leaky02(a0 + ad) - m);
            ssum += p0;
            acc += p0 * v0;
        }
    }

    float inv = 1.f / ssum;
    float o = (lane < 40) ? (acc * inv + bias[lane]) : -INFINITY;

    // log_softmax over the 40 channels (wave-wide reduce)
    float mx = o;
#pragma unroll
    for (int off = 32; off >= 1; off >>= 1) mx = fmaxf(mx, __shfl_xor(mx, off));
    float ex = (lane < 40) ? __expf(o - mx) : 0.f;
    float se = ex;
#pragma unroll
    for (int off = 32; off >= 1; off >>= 1) se += __shfl_xor(se, off);
    float lse = mx + __logf(se);
    if (lane < 40) out[(size_t)node * 40 + lane] = o - lse;
}

// ---------------------------------------------------------------------------

extern "C" void kernel_launch(void* const* d_in, const int* in_sizes, int n_in,
                              void* d_out, int out_size, void* d_ws, size_t ws_size,
                              hipStream_t stream) {
    const float* x      = (const float*)d_in[0];
    const int*   edge   = (const int*)d_in[1];
    const float* W1     = (const float*)d_in[2];
    const float* a_src1 = (const float*)d_in[3];
    const float* a_dst1 = (const float*)d_in[4];
    const float* b1     = (const float*)d_in[5];
    const float* W2     = (const float*)d_in[6];
    const float* a_src2 = (const float*)d_in[7];
    const float* a_dst2 = (const float*)d_in[8];
    const float* b2     = (const float*)d_in[9];
    const float* W3     = (const float*)d_in[10];
    const float* a_src3 = (const float*)d_in[11];
    const float* a_dst3 = (const float*)d_in[12];
    const float* b3     = (const float*)d_in[13];
    float* out = (float*)d_out;

    const int n = in_sizes[0] / 128;   // 10000
    const int e = in_sizes[1] / 2;     // 320000

    char* ws = (char*)d_ws;
    size_t off = 0;
    auto alloc = [&](size_t bytes) -> void* {
        void* p = ws + off;
        off += (bytes + 255) & ~(size_t)255;
        return p;
    };
    float* xp        = (float*)alloc((size_t)n * 256 * 4);
    float* h         = (float*)alloc((size_t)n * 256 * 4);
    float* als       = (float*)alloc((size_t)n * 8 * 4);
    float* ald       = (float*)alloc((size_t)n * 8 * 4);
    int*   row_start = (int*)alloc((size_t)(n + 1) * 4);
    int*   cursor    = (int*)alloc((size_t)n * 4);
    int*   csr_src   = (int*)alloc((size_t)e * 4);
    (void)ws_size;

    const int* srcs = edge;
    const int* dsts = edge + e;

    // --- CSR build (every call: ws is not preserved between replays) ---
    hipMemsetAsync(cursor, 0, (size_t)n * 4, stream);
    count_deg_kernel<<<(e + 255) / 256, 256, 0, stream>>>(dsts, cursor, e);
    scan_deg_kernel<<<1, 1024, 0, stream>>>(cursor, row_start, cursor, n);
    scatter_csr_kernel<<<(e + 255) / 256, 256, 0, stream>>>(srcs, dsts, cursor, csr_src, e);

    const int waves_grid = (n * 64 + 255) / 256;

    // --- Layer 1: 128 -> 8x32, ELU ---
    gemm_f32_64x64<<<dim3((256 + 63) / 64, (n + 63) / 64), 256, 0, stream>>>(x, W1, xp, n, 256, 128);
    al_heads_kernel<<<waves_grid, 256, 0, stream>>>(xp, a_src1, a_dst1, als, ald, n);
    aggregate_h8_kernel<<<waves_grid, 256, 0, stream>>>(xp, als, ald, row_start, csr_src, b1, h, n);

    // --- Layer 2: 256 -> 8x32, ELU ---
    gemm_f32_64x64<<<dim3((256 + 63) / 64, (n + 63) / 64), 256, 0, stream>>>(h, W2, xp, n, 256, 256);
    al_heads_kernel<<<waves_grid, 256, 0, stream>>>(xp, a_src2, a_dst2, als, ald, n);
    aggregate_h8_kernel<<<waves_grid, 256, 0, stream>>>(xp, als, ald, row_start, csr_src, b2, h, n);

    // --- Layer 3: 256 -> 40, H=1, + log_softmax ---
    gemm_f32_64x64<<<dim3(1, (n + 63) / 64), 256, 0, stream>>>(h, W3, xp, n, 40, 256);
    al_out_kernel<<<(n + 255) / 256, 256, 0, stream>>>(xp, a_src3, a_dst3, als, ald, n);
    aggregate_out_kernel<<<waves_grid, 256, 0, stream>>>(xp, als, ald, row_start, csr_src, b3, out, n);
}

// Round 3
// 198.561 us; speedup vs baseline: 1.8051x; 1.3082x over previous
//
#include <hip/hip_runtime.h>
#include <hip/hip_bf16.h>
#include <math.h>

// ---------------------------------------------------------------------------
// MultiLayerGAT: 3x GATConv (PyG-style, self-loops added) + log_softmax.
// N=10000 nodes, E=320000 edges, layers: 128->8x32 (elu) -> 256->8x32 (elu)
// -> 256->40 (H=1) -> log_softmax.
//
// R2: GEMMs moved to bf16 MFMA (v_mfma_f32_16x16x32_bf16, f32 accum).
//   - weights pre-transposed+cast to [N][K] bf16 (tiny one-off kernels)
//   - x cast to bf16 once; aggregate_h8 emits bf16 h directly
//   - 64x64 tile / 4 waves / BK=32, reg-staged LDS with chunk-XOR swizzle
//     (conflict-free ds_read_b128 fragment reads)
// ---------------------------------------------------------------------------

#define DEV_INLINE __device__ __forceinline__

typedef __attribute__((ext_vector_type(8))) short short8;
typedef __attribute__((ext_vector_type(4))) float f32x4;
typedef unsigned short ushort_t;
typedef unsigned int uint_t;

DEV_INLINE float leaky02(float x) { return x > 0.f ? x : 0.2f * x; }
DEV_INLINE float elu1(float x) { return x > 0.f ? x : expm1f(x); }

// round-to-nearest-even f32 -> bf16 (matches numpy/torch)
DEV_INLINE ushort_t f2bf(float f) {
    uint_t u = __float_as_uint(f);
    u += 0x7FFFu + ((u >> 16) & 1u);
    return (ushort_t)(u >> 16);
}

// ---------------- CSR build ----------------

__global__ void count_deg_kernel(const int* __restrict__ dst, int* __restrict__ deg, int e) {
    int i = blockIdx.x * blockDim.x + threadIdx.x;
    if (i < e) atomicAdd(&deg[dst[i]], 1);
}

__global__ __launch_bounds__(1024) void scan_deg_kernel(const int* __restrict__ deg,
                                                        int* __restrict__ row_start,
                                                        int* __restrict__ cursor, int n) {
    __shared__ int sums[1024];
    const int t = threadIdx.x;
    constexpr int ITEMS = 16;               // 1024*16 = 16384 >= n
    const int base = t * ITEMS;
    int local[ITEMS];
    int run = 0;
#pragma unroll
    for (int i = 0; i < ITEMS; ++i) {
        int idx = base + i;
        int v = (idx < n) ? deg[idx] : 0;
        local[i] = run;
        run += v;
    }
    sums[t] = run;
    __syncthreads();
    for (int off = 1; off < 1024; off <<= 1) {
        int v = (t >= off) ? sums[t - off] : 0;
        __syncthreads();
        sums[t] += v;
        __syncthreads();
    }
    int prefix = (t == 0) ? 0 : sums[t - 1];
#pragma unroll
    for (int i = 0; i < ITEMS; ++i) {
        int idx = base + i;
        if (idx < n) {
            int v = prefix + local[i];
            row_start[idx] = v;
            cursor[idx] = v;
        }
    }
    if (t == 1023) row_start[n] = sums[1023];
}

__global__ void scatter_csr_kernel(const int* __restrict__ src, const int* __restrict__ dst,
                                   int* __restrict__ cursor, int* __restrict__ csr_src, int e) {
    int i = blockIdx.x * blockDim.x + threadIdx.x;
    if (i < e) {
        int p = atomicAdd(&cursor[dst[i]], 1);
        csr_src[p] = src[i];
    }
}

// ---------------- casts / transposes ----------------

__global__ void cast_bf16_kernel(const float* __restrict__ in, ushort_t* __restrict__ out, int count4) {
    int i = blockIdx.x * blockDim.x + threadIdx.x;
    if (i >= count4) return;
    float4 v = *(const float4*)(in + (size_t)i * 4);
    ushort4 o;
    o.x = f2bf(v.x); o.y = f2bf(v.y); o.z = f2bf(v.z); o.w = f2bf(v.w);
    *(ushort4*)(out + (size_t)i * 4) = o;
}

// W [K][N] f32 -> WT [N][K] bf16 (tiny matrices; simple is fine)
__global__ void transpose_cast_kernel(const float* __restrict__ W, ushort_t* __restrict__ WT,
                                      int K, int N) {
    int i = blockIdx.x * blockDim.x + threadIdx.x;
    if (i >= K * N) return;
    int k = i / N, n = i - k * N;
    WT[(size_t)n * K + k] = f2bf(W[i]);
}

// ---------------- MFMA GEMM: C[M,N] = A[M,K] @ BT[N,K]^T ----------------
// A, BT bf16 row-major; C f32. Block 256 thr = 4 waves; tile 64x64, BK=32.
// LDS tiles stored as 16B chunks with swizzle c' = (c + (r>>1)) & 3 so both
// the staged writes and the per-wave ds_read_b128 fragment reads spread all
// 8 chunk-banks (conflict-free).

DEV_INLINE int lds_slot(int r, int c) { return r * 4 + ((c + (r >> 1)) & 3); }

__global__ __launch_bounds__(256) void gemm_bf16_mfma(const ushort_t* __restrict__ A,
                                                      const ushort_t* __restrict__ BT,
                                                      float* __restrict__ C,
                                                      int M, int N, int K) {
    __shared__ ushort_t As[64 * 32];
    __shared__ ushort_t Bs[64 * 32];
    const int tid = threadIdx.x;
    const int wave = tid >> 6, lane = tid & 63;
    const int row0 = blockIdx.y * 64;
    const int col0 = blockIdx.x * 64;

    // staging map: thread -> (r = tid>>2, c = tid&3), 16B each = full 4KB tile
    const int sr = tid >> 2, sc = tid & 3;
    const int a_row = row0 + sr;
    const int b_row = col0 + sr;   // n-index into BT

    // fragment read offsets (ushort units)
    const int fr = lane & 15;        // local row within 16-row strip / col within tile
    const int fc = lane >> 4;        // k-chunk 0..3

    f32x4 acc0 = {}, acc1 = {}, acc2 = {}, acc3 = {};

    for (int k0 = 0; k0 < K; k0 += 32) {
        short8 av = {}, bv = {};
        if (a_row < M) av = *(const short8*)(A + (size_t)a_row * K + k0 + sc * 8);
        if (b_row < N) bv = *(const short8*)(BT + (size_t)b_row * K + k0 + sc * 8);
        __syncthreads();   // previous iteration's reads done before overwrite
        *(short8*)(As + lds_slot(sr, sc) * 8) = av;
        *(short8*)(Bs + lds_slot(sr, sc) * 8) = bv;
        __syncthreads();

        const int arow = wave * 16 + fr;
        short8 afrag = *(const short8*)(As + lds_slot(arow, fc) * 8);
        short8 b0 = *(const short8*)(Bs + lds_slot(0 * 16 + fr, fc) * 8);
        short8 b1 = *(const short8*)(Bs + lds_slot(1 * 16 + fr, fc) * 8);
        short8 b2 = *(const short8*)(Bs + lds_slot(2 * 16 + fr, fc) * 8);
        short8 b3 = *(const short8*)(Bs + lds_slot(3 * 16 + fr, fc) * 8);
        acc0 = __builtin_amdgcn_mfma_f32_16x16x32_bf16(afrag, b0, acc0, 0, 0, 0);
        acc1 = __builtin_amdgcn_mfma_f32_16x16x32_bf16(afrag, b1, acc1, 0, 0, 0);
        acc2 = __builtin_amdgcn_mfma_f32_16x16x32_bf16(afrag, b2, acc2, 0, 0, 0);
        acc3 = __builtin_amdgcn_mfma_f32_16x16x32_bf16(afrag, b3, acc3, 0, 0, 0);
    }

    // C/D layout: col = lane&15, row = (lane>>4)*4 + reg
    const int crow = row0 + wave * 16 + (lane >> 4) * 4;
    const int ccol = col0 + (lane & 15);
    f32x4 accs[4] = {acc0, acc1, acc2, acc3};
#pragma unroll
    for (int ct = 0; ct < 4; ++ct) {
        int col = ccol + ct * 16;
        if (col >= N) continue;
#pragma unroll
        for (int j = 0; j < 4; ++j) {
            int row = crow + j;
            if (row < M) C[(size_t)row * N + col] = accs[ct][j];
        }
    }
}

// ---------------- attention logits, H=8, C=32 (HC=256) ----------------

__global__ __launch_bounds__(256) void al_heads_kernel(const float* __restrict__ xp,
                                                       const float* __restrict__ a_src,
                                                       const float* __restrict__ a_dst,
                                                       float* __restrict__ als,
                                                       float* __restrict__ ald, int n) {
    int node = (blockIdx.x * blockDim.x + threadIdx.x) >> 6;
    int lane = threadIdx.x & 63;
    if (node >= n) return;
    float4 xv = *(const float4*)(xp + (size_t)node * 256 + lane * 4);
    float4 as4 = *(const float4*)(a_src + lane * 4);
    float4 ad4 = *(const float4*)(a_dst + lane * 4);
    float ps = xv.x * as4.x + xv.y * as4.y + xv.z * as4.z + xv.w * as4.w;
    float pd = xv.x * ad4.x + xv.y * ad4.y + xv.z * ad4.z + xv.w * ad4.w;
#pragma unroll
    for (int off = 1; off < 8; off <<= 1) {
        ps += __shfl_xor(ps, off);
        pd += __shfl_xor(pd, off);
    }
    if ((lane & 7) == 0) {
        als[node * 8 + (lane >> 3)] = ps;
        ald[node * 8 + (lane >> 3)] = pd;
    }
}

// ---------------- aggregation, layers 1-2 (H=8, C=32) + bias + ELU -> bf16 ----------------

__global__ __launch_bounds__(256) void aggregate_h8_kernel(const float* __restrict__ xp,
                                                           const float* __restrict__ als,
                                                           const float* __restrict__ ald,
                                                           const int* __restrict__ row_start,
                                                           const int* __restrict__ csr_src,
                                                           const float* __restrict__ bias,
                                                           ushort_t* __restrict__ out, int n) {
    int node = (blockIdx.x * blockDim.x + threadIdx.x) >> 6;
    int lane = threadIdx.x & 63;
    if (node >= n) return;
    const int head = lane >> 3;
    const int rs = row_start[node], re = row_start[node + 1];
    const float ad = ald[node * 8 + head];
    const float m = leaky02(als[node * 8 + head] + ad);   // shift = self-loop logit

    float ssum = 1.0f;                                    // exp(e_self - m) == 1
    float4 acc = *(const float4*)(xp + (size_t)node * 256 + lane * 4);

    for (int base = rs; base < re; base += 64) {
        const int cnt = (re - base < 64) ? (re - base) : 64;
        int myi = (lane < cnt) ? csr_src[base + lane] : 0;

        int j = 0;
        for (; j + 4 <= cnt; j += 4) {
            int s0 = __shfl(myi, j);
            int s1 = __shfl(myi, j + 1);
            int s2 = __shfl(myi, j + 2);
            int s3 = __shfl(myi, j + 3);
            float a0 = als[s0 * 8 + head];
            float a1 = als[s1 * 8 + head];
            float a2 = als[s2 * 8 + head];
            float a3 = als[s3 * 8 + head];
            float4 v0 = *(const float4*)(xp + (size_t)s0 * 256 + lane * 4);
            float4 v1 = *(const float4*)(xp + (size_t)s1 * 256 + lane * 4);
            float4 v2 = *(const float4*)(xp + (size_t)s2 * 256 + lane * 4);
            float4 v3 = *(const float4*)(xp + (size_t)s3 * 256 + lane * 4);
            float p0 = __expf(leaky02(a0 + ad) - m);
            float p1 = __expf(leaky02(a1 + ad) - m);
            float p2 = __expf(leaky02(a2 + ad) - m);
            float p3 = __expf(leaky02(a3 + ad) - m);
            ssum += (p0 + p1) + (p2 + p3);
            acc.x += (p0 * v0.x + p1 * v1.x) + (p2 * v2.x + p3 * v3.x);
            acc.y += (p0 * v0.y + p1 * v1.y) + (p2 * v2.y + p3 * v3.y);
            acc.z += (p0 * v0.z + p1 * v1.z) + (p2 * v2.z + p3 * v3.z);
            acc.w += (p0 * v0.w + p1 * v1.w) + (p2 * v2.w + p3 * v3.w);
        }
        for (; j < cnt; ++j) {
            int s0 = __shfl(myi, j);
            float a0 = als[s0 * 8 + head];
            float4 v0 = *(const float4*)(xp + (size_t)s0 * 256 + lane * 4);
            float p0 = __expf(leaky02(a0 + ad) - m);
            ssum += p0;
            acc.x += p0 * v0.x;
            acc.y += p0 * v0.y;
            acc.z += p0 * v0.z;
            acc.w += p0 * v0.w;
        }
    }

    float inv = 1.f / ssum;
    float4 b4 = *(const float4*)(bias + lane * 4);
    ushort4 o;
    o.x = f2bf(elu1(acc.x * inv + b4.x));
    o.y = f2bf(elu1(acc.y * inv + b4.y));
    o.z = f2bf(elu1(acc.z * inv + b4.z));
    o.w = f2bf(elu1(acc.w * inv + b4.w));
    *(ushort4*)(out + (size_t)node * 256 + lane * 4) = o;
}

// ---------------- attention logits layer 3 (H=1, C=40) ----------------

__global__ void al_out_kernel(const float* __restrict__ xp, const float* __restrict__ a_src,
                              const float* __restrict__ a_dst, float* __restrict__ als,
                              float* __restrict__ ald, int n) {
    int i = blockIdx.x * blockDim.x + threadIdx.x;
    if (i >= n) return;
    float s = 0.f, d = 0.f;
#pragma unroll 8
    for (int c = 0; c < 40; ++c) {
        float v = xp[(size_t)i * 40 + c];
        s += v * a_src[c];
        d += v * a_dst[c];
    }
    als[i] = s;
    ald[i] = d;
}

// ---------------- aggregation layer 3 (H=1, C=40) + bias + log_softmax ----------------

__global__ __launch_bounds__(256) void aggregate_out_kernel(const float* __restrict__ xp,
                                                            const float* __restrict__ als,
                                                            const float* __restrict__ ald,
                                                            const int* __restrict__ row_start,
                                                            const int* __restrict__ csr_src,
                                                            const float* __restrict__ bias,
                                                            float* __restrict__ out, int n) {
    int node = (blockIdx.x * blockDim.x + threadIdx.x) >> 6;
    int lane = threadIdx.x & 63;
    if (node >= n) return;
    const int rs = row_start[node], re = row_start[node + 1];
    const float ad = ald[node];
    const float m = leaky02(als[node] + ad);              // shift = self-loop logit

    float ssum = 1.0f;
    float acc = (lane < 40) ? xp[(size_t)node * 40 + lane] : 0.f;

    for (int base = rs; base < re; base += 64) {
        const int cnt = (re - base < 64) ? (re - base) : 64;
        int myi = (lane < cnt) ? csr_src[base + lane] : 0;

        int j = 0;
        for (; j + 4 <= cnt; j += 4) {
            int s0 = __shfl(myi, j);
            int s1 = __shfl(myi, j + 1);
            int s2 = __shfl(myi, j + 2);
            int s3 = __shfl(myi, j + 3);
            float a0 = als[s0];
            float a1 = als[s1];
            float a2 = als[s2];
            float a3 = als[s3];
            float v0 = (lane < 40) ? xp[(size_t)s0 * 40 + lane] : 0.f;
            float v1 = (lane < 40) ? xp[(size_t)s1 * 40 + lane] : 0.f;
            float v2 = (lane < 40) ? xp[(size_t)s2 * 40 + lane] : 0.f;
            float v3 = (lane < 40) ? xp[(size_t)s3 * 40 + lane] : 0.f;
            float p0 = __expf(leaky02(a0 + ad) - m);
            float p1 = __expf(leaky02(a1 + ad) - m);
            float p2 = __expf(leaky02(a2 + ad) - m);
            float p3 = __expf(leaky02(a3 + ad) - m);
            ssum += (p0 + p1) + (p2 + p3);
            acc += (p0 * v0 + p1 * v1) + (p2 * v2 + p3 * v3);
        }
        for (; j < cnt; ++j) {
            int s0 = __shfl(myi, j);
            float a0 = als[s0];
            float v0 = (lane < 40) ? xp[(size_t)s0 * 40 + lane] : 0.f;
            float p0 = __expf(leaky02(a0 + ad) - m);
            ssum += p0;
            acc += p0 * v0;
        }
    }

    float inv = 1.f / ssum;
    float o = (lane < 40) ? (acc * inv + bias[lane]) : -INFINITY;

    // log_softmax over the 40 channels (wave-wide reduce)
    float mx = o;
#pragma unroll
    for (int off = 32; off >= 1; off >>= 1) mx = fmaxf(mx, __shfl_xor(mx, off));
    float ex = (lane < 40) ? __expf(o - mx) : 0.f;
    float se = ex;
#pragma unroll
    for (int off = 32; off >= 1; off >>= 1) se += __shfl_xor(se, off);
    float lse = mx + __logf(se);
    if (lane < 40) out[(size_t)node * 40 + lane] = o - lse;
}

// ---------------------------------------------------------------------------

extern "C" void kernel_launch(void* const* d_in, const int* in_sizes, int n_in,
                              void* d_out, int out_size, void* d_ws, size_t ws_size,
                              hipStream_t stream) {
    const float* x      = (const float*)d_in[0];
    const int*   edge   = (const int*)d_in[1];
    const float* W1     = (const float*)d_in[2];
    const float* a_src1 = (const float*)d_in[3];
    const float* a_dst1 = (const float*)d_in[4];
    const float* b1     = (const float*)d_in[5];
    const float* W2     = (const float*)d_in[6];
    const float* a_src2 = (const float*)d_in[7];
    const float* a_dst2 = (const float*)d_in[8];
    const float* b2     = (const float*)d_in[9];
    const float* W3     = (const float*)d_in[10];
    const float* a_src3 = (const float*)d_in[11];
    const float* a_dst3 = (const float*)d_in[12];
    const float* b3     = (const float*)d_in[13];
    float* out = (float*)d_out;

    const int n = in_sizes[0] / 128;   // 10000
    const int e = in_sizes[1] / 2;     // 320000

    char* ws = (char*)d_ws;
    size_t off = 0;
    auto alloc = [&](size_t bytes) -> void* {
        void* p = ws + off;
        off += (bytes + 255) & ~(size_t)255;
        return p;
    };
    float*    xp        = (float*)alloc((size_t)n * 256 * 4);
    ushort_t* h_bf      = (ushort_t*)alloc((size_t)n * 256 * 2);
    ushort_t* x_bf      = (ushort_t*)alloc((size_t)n * 128 * 2);
    ushort_t* W1T       = (ushort_t*)alloc((size_t)256 * 128 * 2);
    ushort_t* W2T       = (ushort_t*)alloc((size_t)256 * 256 * 2);
    ushort_t* W3T       = (ushort_t*)alloc((size_t)40 * 256 * 2);
    float*    als       = (float*)alloc((size_t)n * 8 * 4);
    float*    ald       = (float*)alloc((size_t)n * 8 * 4);
    int*      row_start = (int*)alloc((size_t)(n + 1) * 4);
    int*      cursor    = (int*)alloc((size_t)n * 4);
    int*      csr_src   = (int*)alloc((size_t)e * 4);
    (void)ws_size;

    const int* srcs = edge;
    const int* dsts = edge + e;

    // --- prep: casts / transposes + CSR build ---
    cast_bf16_kernel<<<(n * 128 / 4 + 255) / 256, 256, 0, stream>>>(x, x_bf, n * 128 / 4);
    transpose_cast_kernel<<<(128 * 256 + 255) / 256, 256, 0, stream>>>(W1, W1T, 128, 256);
    transpose_cast_kernel<<<(256 * 256 + 255) / 256, 256, 0, stream>>>(W2, W2T, 256, 256);
    transpose_cast_kernel<<<(256 * 40 + 255) / 256, 256, 0, stream>>>(W3, W3T, 256, 40);

    hipMemsetAsync(cursor, 0, (size_t)n * 4, stream);
    count_deg_kernel<<<(e + 255) / 256, 256, 0, stream>>>(dsts, cursor, e);
    scan_deg_kernel<<<1, 1024, 0, stream>>>(cursor, row_start, cursor, n);
    scatter_csr_kernel<<<(e + 255) / 256, 256, 0, stream>>>(srcs, dsts, cursor, csr_src, e);

    const int waves_grid = (n * 64 + 255) / 256;
    const int mby = (n + 63) / 64;

    // --- Layer 1: 128 -> 8x32, ELU ---
    gemm_bf16_mfma<<<dim3(4, mby), 256, 0, stream>>>(x_bf, W1T, xp, n, 256, 128);
    al_heads_kernel<<<waves_grid, 256, 0, stream>>>(xp, a_src1, a_dst1, als, ald, n);
    aggregate_h8_kernel<<<waves_grid, 256, 0, stream>>>(xp, als, ald, row_start, csr_src, b1, h_bf, n);

    // --- Layer 2: 256 -> 8x32, ELU ---
    gemm_bf16_mfma<<<dim3(4, mby), 256, 0, stream>>>(h_bf, W2T, xp, n, 256, 256);
    al_heads_kernel<<<waves_grid, 256, 0, stream>>>(xp, a_src2, a_dst2, als, ald, n);
    aggregate_h8_kernel<<<waves_grid, 256, 0, stream>>>(xp, als, ald, row_start, csr_src, b2, h_bf, n);

    // --- Layer 3: 256 -> 40, H=1, + log_softmax ---
    gemm_bf16_mfma<<<dim3(1, mby), 256, 0, stream>>>(h_bf, W3T, xp, n, 40, 256);
    al_out_kernel<<<(n + 255) / 256, 256, 0, stream>>>(xp, a_src3, a_dst3, als, ald, n);
    aggregate_out_kernel<<<waves_grid, 256, 0, stream>>>(xp, als, ald, row_start, csr_src, b3, out, n);
}

// Round 4
// 167.182 us; speedup vs baseline: 2.1439x; 1.1877x over previous
//
#include <hip/hip_runtime.h>
#include <hip/hip_bf16.h>
#include <math.h>

// ---------------------------------------------------------------------------
// MultiLayerGAT: 3x GATConv (PyG-style, self-loops added) + log_softmax.
// N=10000 nodes, E=320000 edges, layers: 128->8x32 (elu) -> 256->8x32 (elu)
// -> 256->40 (H=1) -> log_softmax.
//
// R3: all gathered feature tensors stored bf16 (GEMM epilogue emits bf16,
// aggregation gathers bf16 -> halves the dominant L2/L3 gather traffic).
// Prep casts/transposes fused into one kernel. f32 accumulation everywhere.
// ---------------------------------------------------------------------------

#define DEV_INLINE __device__ __forceinline__

typedef __attribute__((ext_vector_type(8))) short short8;
typedef __attribute__((ext_vector_type(4))) float f32x4;
typedef unsigned short ushort_t;
typedef unsigned int uint_t;

DEV_INLINE float leaky02(float x) { return x > 0.f ? x : 0.2f * x; }
DEV_INLINE float elu1(float x) { return x > 0.f ? x : expm1f(x); }

// round-to-nearest-even f32 -> bf16
DEV_INLINE ushort_t f2bf(float f) {
    uint_t u = __float_as_uint(f);
    u += 0x7FFFu + ((u >> 16) & 1u);
    return (ushort_t)(u >> 16);
}
DEV_INLINE float bf2f(ushort_t u) { return __uint_as_float(((uint_t)u) << 16); }

// ---------------- CSR build ----------------

__global__ void count_deg_kernel(const int* __restrict__ dst, int* __restrict__ deg, int e) {
    int i = blockIdx.x * blockDim.x + threadIdx.x;
    if (i < e) atomicAdd(&deg[dst[i]], 1);
}

__global__ __launch_bounds__(1024) void scan_deg_kernel(const int* __restrict__ deg,
                                                        int* __restrict__ row_start,
                                                        int* __restrict__ cursor, int n) {
    __shared__ int sums[1024];
    const int t = threadIdx.x;
    constexpr int ITEMS = 16;               // 1024*16 = 16384 >= n
    const int base = t * ITEMS;
    int local[ITEMS];
    int run = 0;
#pragma unroll
    for (int i = 0; i < ITEMS; ++i) {
        int idx = base + i;
        int v = (idx < n) ? deg[idx] : 0;
        local[i] = run;
        run += v;
    }
    sums[t] = run;
    __syncthreads();
    for (int off = 1; off < 1024; off <<= 1) {
        int v = (t >= off) ? sums[t - off] : 0;
        __syncthreads();
        sums[t] += v;
        __syncthreads();
    }
    int prefix = (t == 0) ? 0 : sums[t - 1];
#pragma unroll
    for (int i = 0; i < ITEMS; ++i) {
        int idx = base + i;
        if (idx < n) {
            int v = prefix + local[i];
            row_start[idx] = v;
            cursor[idx] = v;
        }
    }
    if (t == 1023) row_start[n] = sums[1023];
}

__global__ void scatter_csr_kernel(const int* __restrict__ src, const int* __restrict__ dst,
                                   int* __restrict__ cursor, int* __restrict__ csr_src, int e) {
    int i = blockIdx.x * blockDim.x + threadIdx.x;
    if (i < e) {
        int p = atomicAdd(&cursor[dst[i]], 1);
        csr_src[p] = src[i];
    }
}

// ---------------- fused prep: cast x + transpose/cast W1,W2,W3 ----------------

__global__ void prep_kernel(const float* __restrict__ x, ushort_t* __restrict__ x_bf,
                            const float* __restrict__ W1, ushort_t* __restrict__ W1T,
                            const float* __restrict__ W2, ushort_t* __restrict__ W2T,
                            const float* __restrict__ W3, ushort_t* __restrict__ W3T,
                            int n) {
    int i = blockIdx.x * blockDim.x + threadIdx.x;
    int xcnt = n * 128 / 4;
    if (i < xcnt) {
        float4 v = *(const float4*)(x + (size_t)i * 4);
        ushort4 o;
        o.x = f2bf(v.x); o.y = f2bf(v.y); o.z = f2bf(v.z); o.w = f2bf(v.w);
        *(ushort4*)(x_bf + (size_t)i * 4) = o;
        return;
    }
    i -= xcnt;
    if (i < 128 * 256) {                       // W1 [128][256] -> W1T [256][128]
        int k = i >> 8, c = i & 255;
        W1T[(size_t)c * 128 + k] = f2bf(W1[i]);
        return;
    }
    i -= 128 * 256;
    if (i < 256 * 256) {                       // W2 [256][256] -> W2T [256][256]
        int k = i >> 8, c = i & 255;
        W2T[(size_t)c * 256 + k] = f2bf(W2[i]);
        return;
    }
    i -= 256 * 256;
    if (i < 256 * 40) {                        // W3 [256][40] -> W3T [40][256]
        int k = i / 40, c = i - k * 40;
        W3T[(size_t)c * 256 + k] = f2bf(W3[i]);
        return;
    }
}

// ---------------- MFMA GEMM: C[M,N] = A[M,K] @ BT[N,K]^T, bf16 in/out ----------------

DEV_INLINE int lds_slot(int r, int c) { return r * 4 + ((c + (r >> 1)) & 3); }

__global__ __launch_bounds__(256) void gemm_bf16_mfma(const ushort_t* __restrict__ A,
                                                      const ushort_t* __restrict__ BT,
                                                      ushort_t* __restrict__ C,
                                                      int M, int N, int K) {
    __shared__ ushort_t As[64 * 32];
    __shared__ ushort_t Bs[64 * 32];
    const int tid = threadIdx.x;
    const int wave = tid >> 6, lane = tid & 63;
    const int row0 = blockIdx.y * 64;
    const int col0 = blockIdx.x * 64;

    const int sr = tid >> 2, sc = tid & 3;
    const int a_row = row0 + sr;
    const int b_row = col0 + sr;

    const int fr = lane & 15;
    const int fc = lane >> 4;

    f32x4 acc0 = {}, acc1 = {}, acc2 = {}, acc3 = {};

    for (int k0 = 0; k0 < K; k0 += 32) {
        short8 av = {}, bv = {};
        if (a_row < M) av = *(const short8*)(A + (size_t)a_row * K + k0 + sc * 8);
        if (b_row < N) bv = *(const short8*)(BT + (size_t)b_row * K + k0 + sc * 8);
        __syncthreads();
        *(short8*)(As + lds_slot(sr, sc) * 8) = av;
        *(short8*)(Bs + lds_slot(sr, sc) * 8) = bv;
        __syncthreads();

        const int arow = wave * 16 + fr;
        short8 afrag = *(const short8*)(As + lds_slot(arow, fc) * 8);
        short8 b0 = *(const short8*)(Bs + lds_slot(0 * 16 + fr, fc) * 8);
        short8 b1 = *(const short8*)(Bs + lds_slot(1 * 16 + fr, fc) * 8);
        short8 b2 = *(const short8*)(Bs + lds_slot(2 * 16 + fr, fc) * 8);
        short8 b3 = *(const short8*)(Bs + lds_slot(3 * 16 + fr, fc) * 8);
        acc0 = __builtin_amdgcn_mfma_f32_16x16x32_bf16(afrag, b0, acc0, 0, 0, 0);
        acc1 = __builtin_amdgcn_mfma_f32_16x16x32_bf16(afrag, b1, acc1, 0, 0, 0);
        acc2 = __builtin_amdgcn_mfma_f32_16x16x32_bf16(afrag, b2, acc2, 0, 0, 0);
        acc3 = __builtin_amdgcn_mfma_f32_16x16x32_bf16(afrag, b3, acc3, 0, 0, 0);
    }

    // C/D layout: col = lane&15, row = (lane>>4)*4 + reg
    const int crow = row0 + wave * 16 + (lane >> 4) * 4;
    const int ccol = col0 + (lane & 15);
    f32x4 accs[4] = {acc0, acc1, acc2, acc3};
#pragma unroll
    for (int ct = 0; ct < 4; ++ct) {
        int col = ccol + ct * 16;
        if (col >= N) continue;
#pragma unroll
        for (int j = 0; j < 4; ++j) {
            int row = crow + j;
            if (row < M) C[(size_t)row * N + col] = f2bf(accs[ct][j]);
        }
    }
}

// ---------------- attention logits, H=8, C=32 (HC=256, bf16 xp) ----------------

__global__ __launch_bounds__(256) void al_heads_kernel(const ushort_t* __restrict__ xp,
                                                       const float* __restrict__ a_src,
                                                       const float* __restrict__ a_dst,
                                                       float* __restrict__ als,
                                                       float* __restrict__ ald, int n) {
    int node = (blockIdx.x * blockDim.x + threadIdx.x) >> 6;
    int lane = threadIdx.x & 63;
    if (node >= n) return;
    ushort4 xv = *(const ushort4*)(xp + (size_t)node * 256 + lane * 4);
    float x0 = bf2f(xv.x), x1 = bf2f(xv.y), x2 = bf2f(xv.z), x3 = bf2f(xv.w);
    float4 as4 = *(const float4*)(a_src + lane * 4);
    float4 ad4 = *(const float4*)(a_dst + lane * 4);
    float ps = x0 * as4.x + x1 * as4.y + x2 * as4.z + x3 * as4.w;
    float pd = x0 * ad4.x + x1 * ad4.y + x2 * ad4.z + x3 * ad4.w;
#pragma unroll
    for (int off = 1; off < 8; off <<= 1) {
        ps += __shfl_xor(ps, off);
        pd += __shfl_xor(pd, off);
    }
    if ((lane & 7) == 0) {
        als[node * 8 + (lane >> 3)] = ps;
        ald[node * 8 + (lane >> 3)] = pd;
    }
}

// ---------------- aggregation, layers 1-2 (H=8, C=32) + bias + ELU, bf16 ----------------

__global__ __launch_bounds__(256) void aggregate_h8_kernel(const ushort_t* __restrict__ xp,
                                                           const float* __restrict__ als,
                                                           const float* __restrict__ ald,
                                                           const int* __restrict__ row_start,
                                                           const int* __restrict__ csr_src,
                                                           const float* __restrict__ bias,
                                                           ushort_t* __restrict__ out, int n) {
    int node = (blockIdx.x * blockDim.x + threadIdx.x) >> 6;
    int lane = threadIdx.x & 63;
    if (node >= n) return;
    const int head = lane >> 3;
    const int rs = row_start[node], re = row_start[node + 1];
    const float ad = ald[node * 8 + head];
    const float m = leaky02(als[node * 8 + head] + ad);   // shift = self-loop logit

    float ssum = 1.0f;                                    // exp(e_self - m) == 1
    ushort4 sv = *(const ushort4*)(xp + (size_t)node * 256 + lane * 4);
    float ax = bf2f(sv.x), ay = bf2f(sv.y), az = bf2f(sv.z), aw = bf2f(sv.w);

    for (int base = rs; base < re; base += 64) {
        const int cnt = (re - base < 64) ? (re - base) : 64;
        int myi = (lane < cnt) ? csr_src[base + lane] : 0;

        int j = 0;
        for (; j + 4 <= cnt; j += 4) {
            int s0 = __shfl(myi, j);
            int s1 = __shfl(myi, j + 1);
            int s2 = __shfl(myi, j + 2);
            int s3 = __shfl(myi, j + 3);
            float a0 = als[s0 * 8 + head];
            float a1 = als[s1 * 8 + head];
            float a2 = als[s2 * 8 + head];
            float a3 = als[s3 * 8 + head];
            ushort4 v0 = *(const ushort4*)(xp + (size_t)s0 * 256 + lane * 4);
            ushort4 v1 = *(const ushort4*)(xp + (size_t)s1 * 256 + lane * 4);
            ushort4 v2 = *(const ushort4*)(xp + (size_t)s2 * 256 + lane * 4);
            ushort4 v3 = *(const ushort4*)(xp + (size_t)s3 * 256 + lane * 4);
            float p0 = __expf(leaky02(a0 + ad) - m);
            float p1 = __expf(leaky02(a1 + ad) - m);
            float p2 = __expf(leaky02(a2 + ad) - m);
            float p3 = __expf(leaky02(a3 + ad) - m);
            ssum += (p0 + p1) + (p2 + p3);
            ax += (p0 * bf2f(v0.x) + p1 * bf2f(v1.x)) + (p2 * bf2f(v2.x) + p3 * bf2f(v3.x));
            ay += (p0 * bf2f(v0.y) + p1 * bf2f(v1.y)) + (p2 * bf2f(v2.y) + p3 * bf2f(v3.y));
            az += (p0 * bf2f(v0.z) + p1 * bf2f(v1.z)) + (p2 * bf2f(v2.z) + p3 * bf2f(v3.z));
            aw += (p0 * bf2f(v0.w) + p1 * bf2f(v1.w)) + (p2 * bf2f(v2.w) + p3 * bf2f(v3.w));
        }
        for (; j < cnt; ++j) {
            int s0 = __shfl(myi, j);
            float a0 = als[s0 * 8 + head];
            ushort4 v0 = *(const ushort4*)(xp + (size_t)s0 * 256 + lane * 4);
            float p0 = __expf(leaky02(a0 + ad) - m);
            ssum += p0;
            ax += p0 * bf2f(v0.x);
            ay += p0 * bf2f(v0.y);
            az += p0 * bf2f(v0.z);
            aw += p0 * bf2f(v0.w);
        }
    }

    float inv = 1.f / ssum;
    float4 b4 = *(const float4*)(bias + lane * 4);
    ushort4 o;
    o.x = f2bf(elu1(ax * inv + b4.x));
    o.y = f2bf(elu1(ay * inv + b4.y));
    o.z = f2bf(elu1(az * inv + b4.z));
    o.w = f2bf(elu1(aw * inv + b4.w));
    *(ushort4*)(out + (size_t)node * 256 + lane * 4) = o;
}

// ---------------- attention logits layer 3 (H=1, C=40, bf16 xp) ----------------

__global__ void al_out_kernel(const ushort_t* __restrict__ xp, const float* __restrict__ a_src,
                              const float* __restrict__ a_dst, float* __restrict__ als,
                              float* __restrict__ ald, int n) {
    int i = blockIdx.x * blockDim.x + threadIdx.x;
    if (i >= n) return;
    float s = 0.f, d = 0.f;
#pragma unroll
    for (int c4 = 0; c4 < 10; ++c4) {
        ushort4 v = *(const ushort4*)(xp + (size_t)i * 40 + c4 * 4);
        float4 a = *(const float4*)(a_src + c4 * 4);
        float4 b = *(const float4*)(a_dst + c4 * 4);
        s += bf2f(v.x) * a.x + bf2f(v.y) * a.y + bf2f(v.z) * a.z + bf2f(v.w) * a.w;
        d += bf2f(v.x) * b.x + bf2f(v.y) * b.y + bf2f(v.z) * b.z + bf2f(v.w) * b.w;
    }
    als[i] = s;
    ald[i] = d;
}

// ---------------- aggregation layer 3 (H=1, C=40) + bias + log_softmax ----------------

__global__ __launch_bounds__(256) void aggregate_out_kernel(const ushort_t* __restrict__ xp,
                                                            const float* __restrict__ als,
                                                            const float* __restrict__ ald,
                                                            const int* __restrict__ row_start,
                                                            const int* __restrict__ csr_src,
                                                            const float* __restrict__ bias,
                                                            float* __restrict__ out, int n) {
    int node = (blockIdx.x * blockDim.x + threadIdx.x) >> 6;
    int lane = threadIdx.x & 63;
    if (node >= n) return;
    const int rs = row_start[node], re = row_start[node + 1];
    const float ad = ald[node];
    const float m = leaky02(als[node] + ad);              // shift = self-loop logit

    float ssum = 1.0f;
    float acc = (lane < 40) ? bf2f(xp[(size_t)node * 40 + lane]) : 0.f;

    for (int base = rs; base < re; base += 64) {
        const int cnt = (re - base < 64) ? (re - base) : 64;
        int myi = (lane < cnt) ? csr_src[base + lane] : 0;

        int j = 0;
        for (; j + 4 <= cnt; j += 4) {
            int s0 = __shfl(myi, j);
            int s1 = __shfl(myi, j + 1);
            int s2 = __shfl(myi, j + 2);
            int s3 = __shfl(myi, j + 3);
            float a0 = als[s0];
            float a1 = als[s1];
            float a2 = als[s2];
            float a3 = als[s3];
            float v0 = (lane < 40) ? bf2f(xp[(size_t)s0 * 40 + lane]) : 0.f;
            float v1 = (lane < 40) ? bf2f(xp[(size_t)s1 * 40 + lane]) : 0.f;
            float v2 = (lane < 40) ? bf2f(xp[(size_t)s2 * 40 + lane]) : 0.f;
            float v3 = (lane < 40) ? bf2f(xp[(size_t)s3 * 40 + lane]) : 0.f;
            float p0 = __expf(leaky02(a0 + ad) - m);
            float p1 = __expf(leaky02(a1 + ad) - m);
            float p2 = __expf(leaky02(a2 + ad) - m);
            float p3 = __expf(leaky02(a3 + ad) - m);
            ssum += (p0 + p1) + (p2 + p3);
            acc += (p0 * v0 + p1 * v1) + (p2 * v2 + p3 * v3);
        }
        for (; j < cnt; ++j) {
            int s0 = __shfl(myi, j);
            float a0 = als[s0];
            float v0 = (lane < 40) ? bf2f(xp[(size_t)s0 * 40 + lane]) : 0.f;
            float p0 = __expf(leaky02(a0 + ad) - m);
            ssum += p0;
            acc += p0 * v0;
        }
    }

    float inv = 1.f / ssum;
    float o = (lane < 40) ? (acc * inv + bias[lane]) : -INFINITY;

    float mx = o;
#pragma unroll
    for (int off = 32; off >= 1; off >>= 1) mx = fmaxf(mx, __shfl_xor(mx, off));
    float ex = (lane < 40) ? __expf(o - mx) : 0.f;
    float se = ex;
#pragma unroll
    for (int off = 32; off >= 1; off >>= 1) se += __shfl_xor(se, off);
    float lse = mx + __logf(se);
    if (lane < 40) out[(size_t)node * 40 + lane] = o - lse;
}

// ---------------------------------------------------------------------------

extern "C" void kernel_launch(void* const* d_in, const int* in_sizes, int n_in,
                              void* d_out, int out_size, void* d_ws, size_t ws_size,
                              hipStream_t stream) {
    const float* x      = (const float*)d_in[0];
    const int*   edge   = (const int*)d_in[1];
    const float* W1     = (const float*)d_in[2];
    const float* a_src1 = (const float*)d_in[3];
    const float* a_dst1 = (const float*)d_in[4];
    const float* b1     = (const float*)d_in[5];
    const float* W2     = (const float*)d_in[6];
    const float* a_src2 = (const float*)d_in[7];
    const float* a_dst2 = (const float*)d_in[8];
    const float* b2     = (const float*)d_in[9];
    const float* W3     = (const float*)d_in[10];
    const float* a_src3 = (const float*)d_in[11];
    const float* a_dst3 = (const float*)d_in[12];
    const float* b3     = (const float*)d_in[13];
    float* out = (float*)d_out;

    const int n = in_sizes[0] / 128;   // 10000
    const int e = in_sizes[1] / 2;     // 320000

    char* ws = (char*)d_ws;
    size_t off = 0;
    auto alloc = [&](size_t bytes) -> void* {
        void* p = ws + off;
        off += (bytes + 255) & ~(size_t)255;
        return p;
    };
    ushort_t* xp        = (ushort_t*)alloc((size_t)n * 256 * 2);   // layer1/2 features bf16
    ushort_t* h_bf      = (ushort_t*)alloc((size_t)n * 256 * 2);
    ushort_t* xp3       = (ushort_t*)alloc((size_t)n * 40 * 2);
    ushort_t* x_bf      = (ushort_t*)alloc((size_t)n * 128 * 2);
    ushort_t* W1T       = (ushort_t*)alloc((size_t)256 * 128 * 2);
    ushort_t* W2T       = (ushort_t*)alloc((size_t)256 * 256 * 2);
    ushort_t* W3T       = (ushort_t*)alloc((size_t)40 * 256 * 2);
    float*    als       = (float*)alloc((size_t)n * 8 * 4);
    float*    ald       = (float*)alloc((size_t)n * 8 * 4);
    int*      row_start = (int*)alloc((size_t)(n + 1) * 4);
    int*      cursor    = (int*)alloc((size_t)n * 4);
    int*      csr_src   = (int*)alloc((size_t)e * 4);
    (void)ws_size;

    const int* srcs = edge;
    const int* dsts = edge + e;

    // --- prep + CSR build ---
    {
        int total = n * 128 / 4 + 128 * 256 + 256 * 256 + 256 * 40;
        prep_kernel<<<(total + 255) / 256, 256, 0, stream>>>(x, x_bf, W1, W1T, W2, W2T, W3, W3T, n);
    }
    hipMemsetAsync(cursor, 0, (size_t)n * 4, stream);
    count_deg_kernel<<<(e + 255) / 256, 256, 0, stream>>>(dsts, cursor, e);
    scan_deg_kernel<<<1, 1024, 0, stream>>>(cursor, row_start, cursor, n);
    scatter_csr_kernel<<<(e + 255) / 256, 256, 0, stream>>>(srcs, dsts, cursor, csr_src, e);

    const int waves_grid = (n * 64 + 255) / 256;
    const int mby = (n + 63) / 64;

    // --- Layer 1: 128 -> 8x32, ELU ---
    gemm_bf16_mfma<<<dim3(4, mby), 256, 0, stream>>>(x_bf, W1T, xp, n, 256, 128);
    al_heads_kernel<<<waves_grid, 256, 0, stream>>>(xp, a_src1, a_dst1, als, ald, n);
    aggregate_h8_kernel<<<waves_grid, 256, 0, stream>>>(xp, als, ald, row_start, csr_src, b1, h_bf, n);

    // --- Layer 2: 256 -> 8x32, ELU ---
    gemm_bf16_mfma<<<dim3(4, mby), 256, 0, stream>>>(h_bf, W2T, xp, n, 256, 256);
    al_heads_kernel<<<waves_grid, 256, 0, stream>>>(xp, a_src2, a_dst2, als, ald, n);
    aggregate_h8_kernel<<<waves_grid, 256, 0, stream>>>(xp, als, ald, row_start, csr_src, b2, h_bf, n);

    // --- Layer 3: 256 -> 40, H=1, + log_softmax ---
    gemm_bf16_mfma<<<dim3(1, mby), 256, 0, stream>>>(h_bf, W3T, xp3, n, 40, 256);
    al_out_kernel<<<(n + 255) / 256, 256, 0, stream>>>(xp3, a_src3, a_dst3, als, ald, n);
    aggregate_out_kernel<<<waves_grid, 256, 0, stream>>>(xp3, als, ald, row_start, csr_src, b3, out, n);
}

// Round 5
// 165.118 us; speedup vs baseline: 2.1707x; 1.0125x over previous
//
#include <hip/hip_runtime.h>
#include <hip/hip_bf16.h>
#include <math.h>

// ---------------------------------------------------------------------------
// MultiLayerGAT: 3x GATConv (PyG-style, self-loops added) + log_softmax.
// N=10000, E=320000; 128->8x32(elu) -> 256->8x32(elu) -> 256->40 -> log_softmax
//
// R4: (1) attention logits folded into GEMMs as 16 extra output columns
//     (w_as/w_ad precomputed in prep; epilogue routes them to f32 als/ald),
//     (2) 14 -> 9 launches (memset folded into prep; scan co-launched with
//     GEMM1 via block-role split), (3) aggregation uses 2 waves/node
//     (channel halves) for 2x latency hiding.
// ---------------------------------------------------------------------------

#define DEV_INLINE __device__ __forceinline__

typedef __attribute__((ext_vector_type(8))) short short8;
typedef __attribute__((ext_vector_type(4))) float f32x4;
typedef unsigned short ushort_t;
typedef unsigned int uint_t;

DEV_INLINE float leaky02(float x) { return x > 0.f ? x : 0.2f * x; }
DEV_INLINE float elu1(float x) { return x > 0.f ? x : expm1f(x); }

DEV_INLINE ushort_t f2bf(float f) {
    uint_t u = __float_as_uint(f);
    u += 0x7FFFu + ((u >> 16) & 1u);
    return (ushort_t)(u >> 16);
}
DEV_INLINE float bf2f(ushort_t u) { return __uint_as_float(((uint_t)u) << 16); }

// ---------------- prep: casts, transposes, al-weight folds, cursor zero ------
// W1T_ext [272][128], W2T_ext [272][256], W3T_ext [42][256]:
//   rows 0..NOUT-1  : W^T (bf16)
//   rows NOUT..+NH-1: w_as[h][k] = sum_c W[k][h*C+c] * a_src[h][c]
//   rows +NH..+2NH-1: w_ad likewise

__global__ void prep_kernel(const float* __restrict__ x, ushort_t* __restrict__ x_bf,
                            const float* __restrict__ W1, ushort_t* __restrict__ W1T,
                            const float* __restrict__ W2, ushort_t* __restrict__ W2T,
                            const float* __restrict__ W3, ushort_t* __restrict__ W3T,
                            const float* __restrict__ as1, const float* __restrict__ ad1,
                            const float* __restrict__ as2, const float* __restrict__ ad2,
                            const float* __restrict__ as3, const float* __restrict__ ad3,
                            int* __restrict__ cursor, int n) {
    int i = blockIdx.x * blockDim.x + threadIdx.x;
    int xcnt = n * 32;                         // n*128/4 float4 groups
    if (i < xcnt) {
        float4 v = *(const float4*)(x + (size_t)i * 4);
        ushort4 o;
        o.x = f2bf(v.x); o.y = f2bf(v.y); o.z = f2bf(v.z); o.w = f2bf(v.w);
        *(ushort4*)(x_bf + (size_t)i * 4) = o;
        return;
    }
    i -= xcnt;
    if (i < 128 * 256) {                       // W1 [128][256] -> rows 0..255 of W1T
        int k = i >> 8, c = i & 255;
        W1T[(size_t)c * 128 + k] = f2bf(W1[i]);
        return;
    }
    i -= 128 * 256;
    if (i < 256 * 256) {                       // W2
        int k = i >> 8, c = i & 255;
        W2T[(size_t)c * 256 + k] = f2bf(W2[i]);
        return;
    }
    i -= 256 * 256;
    if (i < 256 * 40) {                        // W3 [256][40] -> rows 0..39 of W3T
        int k = i / 40, c = i - k * 40;
        W3T[(size_t)c * 256 + k] = f2bf(W3[i]);
        return;
    }
    i -= 256 * 40;
    if (i < 1024) {                            // w_as1: h in [0,8), k in [0,128)
        int h = i >> 7, k = i & 127;
        float acc = 0.f;
#pragma unroll
        for (int c = 0; c < 32; ++c) acc += W1[k * 256 + h * 32 + c] * as1[h * 32 + c];
        W1T[(size_t)(256 + h) * 128 + k] = f2bf(acc);
        return;
    }
    i -= 1024;
    if (i < 1024) {                            // w_ad1
        int h = i >> 7, k = i & 127;
        float acc = 0.f;
#pragma unroll
        for (int c = 0; c < 32; ++c) acc += W1[k * 256 + h * 32 + c] * ad1[h * 32 + c];
        W1T[(size_t)(264 + h) * 128 + k] = f2bf(acc);
        return;
    }
    i -= 1024;
    if (i < 2048) {                            // w_as2: h in [0,8), k in [0,256)
        int h = i >> 8, k = i & 255;
        float acc = 0.f;
#pragma unroll
        for (int c = 0; c < 32; ++c) acc += W2[k * 256 + h * 32 + c] * as2[h * 32 + c];
        W2T[(size_t)(256 + h) * 256 + k] = f2bf(acc);
        return;
    }
    i -= 2048;
    if (i < 2048) {                            // w_ad2
        int h = i >> 8, k = i & 255;
        float acc = 0.f;
#pragma unroll
        for (int c = 0; c < 32; ++c) acc += W2[k * 256 + h * 32 + c] * ad2[h * 32 + c];
        W2T[(size_t)(264 + h) * 256 + k] = f2bf(acc);
        return;
    }
    i -= 2048;
    if (i < 256) {                             // w_as3: k in [0,256)
        float acc = 0.f;
#pragma unroll
        for (int c = 0; c < 40; ++c) acc += W3[i * 40 + c] * as3[c];
        W3T[(size_t)40 * 256 + i] = f2bf(acc);
        return;
    }
    i -= 256;
    if (i < 256) {                             // w_ad3
        float acc = 0.f;
#pragma unroll
        for (int c = 0; c < 40; ++c) acc += W3[i * 40 + c] * ad3[c];
        W3T[(size_t)41 * 256 + i] = f2bf(acc);
        return;
    }
    i -= 256;
    if (i < n) cursor[i] = 0;
}

// ---------------- CSR build ----------------

__global__ void count_deg_kernel(const int* __restrict__ dst, int* __restrict__ deg, int e) {
    int i4 = (blockIdx.x * blockDim.x + threadIdx.x) * 4;
    if (i4 + 3 < e) {
        int4 d = *(const int4*)(dst + i4);
        atomicAdd(&deg[d.x], 1); atomicAdd(&deg[d.y], 1);
        atomicAdd(&deg[d.z], 1); atomicAdd(&deg[d.w], 1);
    } else {
        for (int k = i4; k < e; ++k) atomicAdd(&deg[dst[k]], 1);
    }
}

__global__ void scatter_csr_kernel(const int* __restrict__ src, const int* __restrict__ dst,
                                   int* __restrict__ cursor, int* __restrict__ csr_src, int e) {
    int i4 = (blockIdx.x * blockDim.x + threadIdx.x) * 4;
    if (i4 + 3 < e) {
        int4 d = *(const int4*)(dst + i4);
        int4 s = *(const int4*)(src + i4);
        csr_src[atomicAdd(&cursor[d.x], 1)] = s.x;
        csr_src[atomicAdd(&cursor[d.y], 1)] = s.y;
        csr_src[atomicAdd(&cursor[d.z], 1)] = s.z;
        csr_src[atomicAdd(&cursor[d.w], 1)] = s.w;
    } else {
        for (int k = i4; k < e; ++k) {
            int p = atomicAdd(&cursor[dst[k]], 1);
            csr_src[p] = src[k];
        }
    }
}

// 256-thread scan over n<=10240 (reads deg==cursor, writes row_start + cursor)
DEV_INLINE void scan_body(const int* __restrict__ deg, int* __restrict__ row_start,
                          int* __restrict__ cursor, int n) {
    __shared__ int sums[256];
    const int t = threadIdx.x;
    constexpr int ITEMS = 40;                  // 256*40 = 10240 >= n
    const int base = t * ITEMS;
    int local[ITEMS];
    int run = 0;
#pragma unroll
    for (int i = 0; i < ITEMS; ++i) {
        int idx = base + i;
        int v = (idx < n) ? deg[idx] : 0;
        local[i] = run;
        run += v;
    }
    sums[t] = run;
    __syncthreads();
    for (int off = 1; off < 256; off <<= 1) {
        int v = (t >= off) ? sums[t - off] : 0;
        __syncthreads();
        sums[t] += v;
        __syncthreads();
    }
    int prefix = (t == 0) ? 0 : sums[t - 1];
#pragma unroll
    for (int i = 0; i < ITEMS; ++i) {
        int idx = base + i;
        if (idx < n) {
            int v = prefix + local[i];
            row_start[idx] = v;
            cursor[idx] = v;
        }
    }
    if (t == 255) row_start[n] = sums[255];
}

// ---------------- MFMA GEMM body: C[M,0..NOUT) bf16, cols NOUT..NOUT+2NH -> als/ald f32
// A [M][K] bf16, BT [NTOT][K] bf16. 4 waves, 64x64 tile, BK=32, swizzled LDS.

DEV_INLINE int lds_slot(int r, int c) { return r * 4 + ((c + (r >> 1)) & 3); }

DEV_INLINE void gemm_body(const ushort_t* __restrict__ A, const ushort_t* __restrict__ BT,
                          ushort_t* __restrict__ C, float* __restrict__ ALS,
                          float* __restrict__ ALD, int M, int NOUT, int NH, int NTOT,
                          int K, int bx, int by) {
    __shared__ ushort_t As[64 * 32];
    __shared__ ushort_t Bs[64 * 32];
    const int tid = threadIdx.x;
    const int wave = tid >> 6, lane = tid & 63;
    const int row0 = by * 64;
    const int col0 = bx * 64;

    const int sr = tid >> 2, sc = tid & 3;
    const int a_row = row0 + sr;
    const int b_row = col0 + sr;

    const int fr = lane & 15;
    const int fc = lane >> 4;

    f32x4 acc0 = {}, acc1 = {}, acc2 = {}, acc3 = {};

    for (int k0 = 0; k0 < K; k0 += 32) {
        short8 av = {}, bv = {};
        if (a_row < M) av = *(const short8*)(A + (size_t)a_row * K + k0 + sc * 8);
        if (b_row < NTOT) bv = *(const short8*)(BT + (size_t)b_row * K + k0 + sc * 8);
        __syncthreads();
        *(short8*)(As + lds_slot(sr, sc) * 8) = av;
        *(short8*)(Bs + lds_slot(sr, sc) * 8) = bv;
        __syncthreads();

        const int arow = wave * 16 + fr;
        short8 afrag = *(const short8*)(As + lds_slot(arow, fc) * 8);
        short8 b0 = *(const short8*)(Bs + lds_slot(0 * 16 + fr, fc) * 8);
        short8 b1 = *(const short8*)(Bs + lds_slot(1 * 16 + fr, fc) * 8);
        short8 b2 = *(const short8*)(Bs + lds_slot(2 * 16 + fr, fc) * 8);
        short8 b3 = *(const short8*)(Bs + lds_slot(3 * 16 + fr, fc) * 8);
        acc0 = __builtin_amdgcn_mfma_f32_16x16x32_bf16(afrag, b0, acc0, 0, 0, 0);
        acc1 = __builtin_amdgcn_mfma_f32_16x16x32_bf16(afrag, b1, acc1, 0, 0, 0);
        acc2 = __builtin_amdgcn_mfma_f32_16x16x32_bf16(afrag, b2, acc2, 0, 0, 0);
        acc3 = __builtin_amdgcn_mfma_f32_16x16x32_bf16(afrag, b3, acc3, 0, 0, 0);
    }

    // C/D layout: col = lane&15, row = (lane>>4)*4 + reg
    const int crow = row0 + wave * 16 + (lane >> 4) * 4;
    const int ccol = col0 + (lane & 15);
    f32x4 accs[4] = {acc0, acc1, acc2, acc3};
#pragma unroll
    for (int ct = 0; ct < 4; ++ct) {
        int col = ccol + ct * 16;
#pragma unroll
        for (int j = 0; j < 4; ++j) {
            int row = crow + j;
            if (row >= M) continue;
            float v = accs[ct][j];
            if (col < NOUT) {
                C[(size_t)row * NOUT + col] = f2bf(v);
            } else {
                int cc = col - NOUT;
                if (cc < NH) ALS[(size_t)row * NH + cc] = v;
                else if (cc < 2 * NH) ALD[(size_t)row * NH + (cc - NH)] = v;
            }
        }
    }
}

__global__ __launch_bounds__(256) void gemm_kernel(const ushort_t* __restrict__ A,
                                                   const ushort_t* __restrict__ BT,
                                                   ushort_t* __restrict__ C,
                                                   float* __restrict__ ALS,
                                                   float* __restrict__ ALD,
                                                   int M, int NOUT, int NH, int NTOT,
                                                   int K, int gx) {
    gemm_body(A, BT, C, ALS, ALD, M, NOUT, NH, NTOT, K, blockIdx.x % gx, blockIdx.x / gx);
}

// block 0: CSR scan; blocks 1..: layer-1 GEMM (independent work, co-scheduled)
__global__ __launch_bounds__(256) void scan_gemm1_kernel(const int* __restrict__ deg,
                                                         int* __restrict__ row_start,
                                                         int* __restrict__ cursor, int n,
                                                         const ushort_t* __restrict__ A,
                                                         const ushort_t* __restrict__ BT,
                                                         ushort_t* __restrict__ C,
                                                         float* __restrict__ ALS,
                                                         float* __restrict__ ALD,
                                                         int M, int K, int gx) {
    if (blockIdx.x == 0) {
        scan_body(deg, row_start, cursor, n);
        return;
    }
    int b = blockIdx.x - 1;
    gemm_body(A, BT, C, ALS, ALD, M, 256, 8, 272, K, b % gx, b / gx);
}

// ---------------- aggregation, layers 1-2: 2 waves/node (128-ch halves) ------

__global__ __launch_bounds__(256) void aggregate_h8_kernel(const ushort_t* __restrict__ xp,
                                                           const float* __restrict__ als,
                                                           const float* __restrict__ ald,
                                                           const int* __restrict__ row_start,
                                                           const int* __restrict__ csr_src,
                                                           const float* __restrict__ bias,
                                                           ushort_t* __restrict__ out, int n) {
    int gw = (blockIdx.x * blockDim.x + threadIdx.x) >> 6;
    int lane = threadIdx.x & 63;
    int node = gw >> 1, half = gw & 1;
    if (node >= n) return;
    const int ch = half * 128 + lane * 2;
    const int head = ch >> 5;
    const int rs = row_start[node], re = row_start[node + 1];
    const float ad = ald[node * 8 + head];
    const float m = leaky02(als[node * 8 + head] + ad);   // shift = self-loop logit

    float ssum = 1.0f;                                    // exp(e_self - m) == 1
    ushort2 sv = *(const ushort2*)(xp + (size_t)node * 256 + ch);
    float c0 = bf2f(sv.x), c1 = bf2f(sv.y);

    for (int base = rs; base < re; base += 64) {
        const int cnt = (re - base < 64) ? (re - base) : 64;
        int myi = (lane < cnt) ? csr_src[base + lane] : 0;

        int j = 0;
        for (; j + 4 <= cnt; j += 4) {
            int s0 = __shfl(myi, j);
            int s1 = __shfl(myi, j + 1);
            int s2 = __shfl(myi, j + 2);
            int s3 = __shfl(myi, j + 3);
            float a0 = als[s0 * 8 + head];
            float a1 = als[s1 * 8 + head];
            float a2 = als[s2 * 8 + head];
            float a3 = als[s3 * 8 + head];
            ushort2 v0 = *(const ushort2*)(xp + (size_t)s0 * 256 + ch);
            ushort2 v1 = *(const ushort2*)(xp + (size_t)s1 * 256 + ch);
            ushort2 v2 = *(const ushort2*)(xp + (size_t)s2 * 256 + ch);
            ushort2 v3 = *(const ushort2*)(xp + (size_t)s3 * 256 + ch);
            float p0 = __expf(leaky02(a0 + ad) - m);
            float p1 = __expf(leaky02(a1 + ad) - m);
            float p2 = __expf(leaky02(a2 + ad) - m);
            float p3 = __expf(leaky02(a3 + ad) - m);
            ssum += (p0 + p1) + (p2 + p3);
            c0 += (p0 * bf2f(v0.x) + p1 * bf2f(v1.x)) + (p2 * bf2f(v2.x) + p3 * bf2f(v3.x));
            c1 += (p0 * bf2f(v0.y) + p1 * bf2f(v1.y)) + (p2 * bf2f(v2.y) + p3 * bf2f(v3.y));
        }
        for (; j < cnt; ++j) {
            int s0 = __shfl(myi, j);
            float a0 = als[s0 * 8 + head];
            ushort2 v0 = *(const ushort2*)(xp + (size_t)s0 * 256 + ch);
            float p0 = __expf(leaky02(a0 + ad) - m);
            ssum += p0;
            c0 += p0 * bf2f(v0.x);
            c1 += p0 * bf2f(v0.y);
        }
    }

    float inv = 1.f / ssum;
    float2 b2 = *(const float2*)(bias + ch);
    ushort2 o;
    o.x = f2bf(elu1(c0 * inv + b2.x));
    o.y = f2bf(elu1(c1 * inv + b2.y));
    *(ushort2*)(out + (size_t)node * 256 + ch) = o;
}

// ---------------- aggregation layer 3 (H=1, C=40) + bias + log_softmax -------

__global__ __launch_bounds__(256) void aggregate_out_kernel(const ushort_t* __restrict__ xp,
                                                            const float* __restrict__ als,
                                                            const float* __restrict__ ald,
                                                            const int* __restrict__ row_start,
                                                            const int* __restrict__ csr_src,
                                                            const float* __restrict__ bias,
                                                            float* __restrict__ out, int n) {
    int node = (blockIdx.x * blockDim.x + threadIdx.x) >> 6;
    int lane = threadIdx.x & 63;
    if (node >= n) return;
    const int rs = row_start[node], re = row_start[node + 1];
    const float ad = ald[node];
    const float m = leaky02(als[node] + ad);              // shift = self-loop logit

    float ssum = 1.0f;
    float acc = (lane < 40) ? bf2f(xp[(size_t)node * 40 + lane]) : 0.f;

    for (int base = rs; base < re; base += 64) {
        const int cnt = (re - base < 64) ? (re - base) : 64;
        int myi = (lane < cnt) ? csr_src[base + lane] : 0;

        int j = 0;
        for (; j + 4 <= cnt; j += 4) {
            int s0 = __shfl(myi, j);
            int s1 = __shfl(myi, j + 1);
            int s2 = __shfl(myi, j + 2);
            int s3 = __shfl(myi, j + 3);
            float a0 = als[s0];
            float a1 = als[s1];
            float a2 = als[s2];
            float a3 = als[s3];
            float v0 = (lane < 40) ? bf2f(xp[(size_t)s0 * 40 + lane]) : 0.f;
            float v1 = (lane < 40) ? bf2f(xp[(size_t)s1 * 40 + lane]) : 0.f;
            float v2 = (lane < 40) ? bf2f(xp[(size_t)s2 * 40 + lane]) : 0.f;
            float v3 = (lane < 40) ? bf2f(xp[(size_t)s3 * 40 + lane]) : 0.f;
            float p0 = __expf(leaky02(a0 + ad) - m);
            float p1 = __expf(leaky02(a1 + ad) - m);
            float p2 = __expf(leaky02(a2 + ad) - m);
            float p3 = __expf(leaky02(a3 + ad) - m);
            ssum += (p0 + p1) + (p2 + p3);
            acc += (p0 * v0 + p1 * v1) + (p2 * v2 + p3 * v3);
        }
        for (; j < cnt; ++j) {
            int s0 = __shfl(myi, j);
            float a0 = als[s0];
            float v0 = (lane < 40) ? bf2f(xp[(size_t)s0 * 40 + lane]) : 0.f;
            float p0 = __expf(leaky02(a0 + ad) - m);
            ssum += p0;
            acc += p0 * v0;
        }
    }

    float inv = 1.f / ssum;
    float o = (lane < 40) ? (acc * inv + bias[lane]) : -INFINITY;

    float mx = o;
#pragma unroll
    for (int off = 32; off >= 1; off >>= 1) mx = fmaxf(mx, __shfl_xor(mx, off));
    float ex = (lane < 40) ? __expf(o - mx) : 0.f;
    float se = ex;
#pragma unroll
    for (int off = 32; off >= 1; off >>= 1) se += __shfl_xor(se, off);
    float lse = mx + __logf(se);
    if (lane < 40) out[(size_t)node * 40 + lane] = o - lse;
}

// ---------------------------------------------------------------------------

extern "C" void kernel_launch(void* const* d_in, const int* in_sizes, int n_in,
                              void* d_out, int out_size, void* d_ws, size_t ws_size,
                              hipStream_t stream) {
    const float* x      = (const float*)d_in[0];
    const int*   edge   = (const int*)d_in[1];
    const float* W1     = (const float*)d_in[2];
    const float* a_src1 = (const float*)d_in[3];
    const float* a_dst1 = (const float*)d_in[4];
    const float* b1     = (const float*)d_in[5];
    const float* W2     = (const float*)d_in[6];
    const float* a_src2 = (const float*)d_in[7];
    const float* a_dst2 = (const float*)d_in[8];
    const float* b2     = (const float*)d_in[9];
    const float* W3     = (const float*)d_in[10];
    const float* a_src3 = (const float*)d_in[11];
    const float* a_dst3 = (const float*)d_in[12];
    const float* b3     = (const float*)d_in[13];
    float* out = (float*)d_out;

    const int n = in_sizes[0] / 128;   // 10000
    const int e = in_sizes[1] / 2;     // 320000

    char* ws = (char*)d_ws;
    size_t off = 0;
    auto alloc = [&](size_t bytes) -> void* {
        void* p = ws + off;
        off += (bytes + 255) & ~(size_t)255;
        return p;
    };
    ushort_t* xp        = (ushort_t*)alloc((size_t)n * 256 * 2);
    ushort_t* h_bf      = (ushort_t*)alloc((size_t)n * 256 * 2);
    ushort_t* xp3       = (ushort_t*)alloc((size_t)n * 40 * 2);
    ushort_t* x_bf      = (ushort_t*)alloc((size_t)n * 128 * 2);
    ushort_t* W1T       = (ushort_t*)alloc((size_t)272 * 128 * 2);
    ushort_t* W2T       = (ushort_t*)alloc((size_t)272 * 256 * 2);
    ushort_t* W3T       = (ushort_t*)alloc((size_t)42 * 256 * 2);
    float*    als       = (float*)alloc((size_t)n * 8 * 4);
    float*    ald       = (float*)alloc((size_t)n * 8 * 4);
    int*      row_start = (int*)alloc((size_t)(n + 1) * 4);
    int*      cursor    = (int*)alloc((size_t)n * 4);
    int*      csr_src   = (int*)alloc((size_t)e * 4);
    (void)ws_size;

    const int* srcs = edge;
    const int* dsts = edge + e;

    const int mby = (n + 63) / 64;             // 157
    const int e4blocks = ((e + 3) / 4 + 255) / 256;

    // K1: prep (casts, transposes, folds, cursor zero)
    {
        int total = n * 32 + 128 * 256 + 256 * 256 + 256 * 40 + 1024 + 1024 + 2048 + 2048 + 256 + 256 + n;
        prep_kernel<<<(total + 255) / 256, 256, 0, stream>>>(
            x, x_bf, W1, W1T, W2, W2T, W3, W3T,
            a_src1, a_dst1, a_src2, a_dst2, a_src3, a_dst3, cursor, n);
    }
    // K2: degree count
    count_deg_kernel<<<e4blocks, 256, 0, stream>>>(dsts, cursor, e);
    // K3: scan (block 0) || layer-1 GEMM (blocks 1..)
    scan_gemm1_kernel<<<1 + 5 * mby, 256, 0, stream>>>(cursor, row_start, cursor, n,
                                                       x_bf, W1T, xp, als, ald, n, 128, 5);
    // K4: CSR scatter
    scatter_csr_kernel<<<e4blocks, 256, 0, stream>>>(srcs, dsts, cursor, csr_src, e);

    const int agg_grid = (n * 2 * 64 + 255) / 256;   // 2 waves/node
    const int agg_out_grid = (n * 64 + 255) / 256;

    // K5: layer-1 aggregation (+bias+ELU) -> h_bf
    aggregate_h8_kernel<<<agg_grid, 256, 0, stream>>>(xp, als, ald, row_start, csr_src, b1, h_bf, n);
    // K6: layer-2 GEMM (+al fold)
    gemm_kernel<<<5 * mby, 256, 0, stream>>>(h_bf, W2T, xp, als, ald, n, 256, 8, 272, 256, 5);
    // K7: layer-2 aggregation -> h_bf
    aggregate_h8_kernel<<<agg_grid, 256, 0, stream>>>(xp, als, ald, row_start, csr_src, b2, h_bf, n);
    // K8: layer-3 GEMM (+al fold)
    gemm_kernel<<<1 * mby, 256, 0, stream>>>(h_bf, W3T, xp3, als, ald, n, 40, 1, 42, 256, 1);
    // K9: layer-3 aggregation + bias + log_softmax
    aggregate_out_kernel<<<agg_out_grid, 256, 0, stream>>>(xp3, als, ald, row_start, csr_src, b3, out, n);
}

// Round 6
// 146.283 us; speedup vs baseline: 2.4502x; 1.1288x over previous
//
#include <hip/hip_runtime.h>
#include <hip/hip_bf16.h>
#include <math.h>

// ---------------------------------------------------------------------------
// MultiLayerGAT: 3x GATConv (PyG-style, self-loops added) + log_softmax.
// N=10000, E=320000; 128->8x32(elu) -> 256->8x32(elu) -> 256->40 -> log_softmax
//
// R5: aggregation restructured for max bytes/load-instruction:
//   - 1 wave/node, 2 edges processed per step (half-waves own even/odd edges),
//     16B short8 gathers (8 ch/lane), cross-half combine via shfl_xor(32).
//   - aggregate_out same two-edge split.
//   - count_deg fused into prep kernel (block roles); cursor zero via memset.
// ---------------------------------------------------------------------------

#define DEV_INLINE __device__ __forceinline__

typedef __attribute__((ext_vector_type(8))) short short8;
typedef __attribute__((ext_vector_type(4))) float f32x4;
typedef unsigned short ushort_t;
typedef unsigned int uint_t;

DEV_INLINE float leaky02(float x) { return x > 0.f ? x : 0.2f * x; }
DEV_INLINE float elu1(float x) { return x > 0.f ? x : expm1f(x); }

DEV_INLINE ushort_t f2bf(float f) {
    uint_t u = __float_as_uint(f);
    u += 0x7FFFu + ((u >> 16) & 1u);
    return (ushort_t)(u >> 16);
}
DEV_INLINE float bf2f(ushort_t u) { return __uint_as_float(((uint_t)u) << 16); }

// ---------------- prep body: casts, transposes, al-weight folds --------------
// W1T_ext [272][128], W2T_ext [272][256], W3T_ext [42][256]:
//   rows 0..NOUT-1  : W^T (bf16)
//   rows NOUT..+NH-1: w_as[h][k] = sum_c W[k][h*C+c] * a_src[h][c]
//   rows +NH..+2NH-1: w_ad likewise

DEV_INLINE void prep_body(int i,
                          const float* __restrict__ x, ushort_t* __restrict__ x_bf,
                          const float* __restrict__ W1, ushort_t* __restrict__ W1T,
                          const float* __restrict__ W2, ushort_t* __restrict__ W2T,
                          const float* __restrict__ W3, ushort_t* __restrict__ W3T,
                          const float* __restrict__ as1, const float* __restrict__ ad1,
                          const float* __restrict__ as2, const float* __restrict__ ad2,
                          const float* __restrict__ as3, const float* __restrict__ ad3,
                          int n) {
    int xcnt = n * 32;                         // n*128/4 float4 groups
    if (i < xcnt) {
        float4 v = *(const float4*)(x + (size_t)i * 4);
        ushort4 o;
        o.x = f2bf(v.x); o.y = f2bf(v.y); o.z = f2bf(v.z); o.w = f2bf(v.w);
        *(ushort4*)(x_bf + (size_t)i * 4) = o;
        return;
    }
    i -= xcnt;
    if (i < 128 * 256) {                       // W1 [128][256] -> rows 0..255
        int k = i >> 8, c = i & 255;
        W1T[(size_t)c * 128 + k] = f2bf(W1[i]);
        return;
    }
    i -= 128 * 256;
    if (i < 256 * 256) {                       // W2
        int k = i >> 8, c = i & 255;
        W2T[(size_t)c * 256 + k] = f2bf(W2[i]);
        return;
    }
    i -= 256 * 256;
    if (i < 256 * 40) {                        // W3 [256][40] -> rows 0..39
        int k = i / 40, c = i - k * 40;
        W3T[(size_t)c * 256 + k] = f2bf(W3[i]);
        return;
    }
    i -= 256 * 40;
    if (i < 1024) {                            // w_as1
        int h = i >> 7, k = i & 127;
        float acc = 0.f;
#pragma unroll
        for (int c = 0; c < 32; ++c) acc += W1[k * 256 + h * 32 + c] * as1[h * 32 + c];
        W1T[(size_t)(256 + h) * 128 + k] = f2bf(acc);
        return;
    }
    i -= 1024;
    if (i < 1024) {                            // w_ad1
        int h = i >> 7, k = i & 127;
        float acc = 0.f;
#pragma unroll
        for (int c = 0; c < 32; ++c) acc += W1[k * 256 + h * 32 + c] * ad1[h * 32 + c];
        W1T[(size_t)(264 + h) * 128 + k] = f2bf(acc);
        return;
    }
    i -= 1024;
    if (i < 2048) {                            // w_as2
        int h = i >> 8, k = i & 255;
        float acc = 0.f;
#pragma unroll
        for (int c = 0; c < 32; ++c) acc += W2[k * 256 + h * 32 + c] * as2[h * 32 + c];
        W2T[(size_t)(256 + h) * 256 + k] = f2bf(acc);
        return;
    }
    i -= 2048;
    if (i < 2048) {                            // w_ad2
        int h = i >> 8, k = i & 255;
        float acc = 0.f;
#pragma unroll
        for (int c = 0; c < 32; ++c) acc += W2[k * 256 + h * 32 + c] * ad2[h * 32 + c];
        W2T[(size_t)(264 + h) * 256 + k] = f2bf(acc);
        return;
    }
    i -= 2048;
    if (i < 256) {                             // w_as3
        float acc = 0.f;
#pragma unroll
        for (int c = 0; c < 40; ++c) acc += W3[i * 40 + c] * as3[c];
        W3T[(size_t)40 * 256 + i] = f2bf(acc);
        return;
    }
    i -= 256;
    if (i < 256) {                             // w_ad3
        float acc = 0.f;
#pragma unroll
        for (int c = 0; c < 40; ++c) acc += W3[i * 40 + c] * ad3[c];
        W3T[(size_t)41 * 256 + i] = f2bf(acc);
        return;
    }
}

// blocks [0, countBlocks): degree count; blocks [countBlocks, ..): prep
__global__ void prep_count_kernel(const float* __restrict__ x, ushort_t* __restrict__ x_bf,
                                  const float* __restrict__ W1, ushort_t* __restrict__ W1T,
                                  const float* __restrict__ W2, ushort_t* __restrict__ W2T,
                                  const float* __restrict__ W3, ushort_t* __restrict__ W3T,
                                  const float* __restrict__ as1, const float* __restrict__ ad1,
                                  const float* __restrict__ as2, const float* __restrict__ ad2,
                                  const float* __restrict__ as3, const float* __restrict__ ad3,
                                  const int* __restrict__ dst, int* __restrict__ deg,
                                  int e, int countBlocks, int n) {
    if (blockIdx.x < countBlocks) {
        int i4 = (blockIdx.x * blockDim.x + threadIdx.x) * 4;
        if (i4 + 3 < e) {
            int4 d = *(const int4*)(dst + i4);
            atomicAdd(&deg[d.x], 1); atomicAdd(&deg[d.y], 1);
            atomicAdd(&deg[d.z], 1); atomicAdd(&deg[d.w], 1);
        } else {
            for (int k = i4; k < e; ++k) atomicAdd(&deg[dst[k]], 1);
        }
        return;
    }
    int i = (blockIdx.x - countBlocks) * blockDim.x + threadIdx.x;
    prep_body(i, x, x_bf, W1, W1T, W2, W2T, W3, W3T, as1, ad1, as2, ad2, as3, ad3, n);
}

// ---------------- CSR scatter ----------------

__global__ void scatter_csr_kernel(const int* __restrict__ src, const int* __restrict__ dst,
                                   int* __restrict__ cursor, int* __restrict__ csr_src, int e) {
    int i4 = (blockIdx.x * blockDim.x + threadIdx.x) * 4;
    if (i4 + 3 < e) {
        int4 d = *(const int4*)(dst + i4);
        int4 s = *(const int4*)(src + i4);
        csr_src[atomicAdd(&cursor[d.x], 1)] = s.x;
        csr_src[atomicAdd(&cursor[d.y], 1)] = s.y;
        csr_src[atomicAdd(&cursor[d.z], 1)] = s.z;
        csr_src[atomicAdd(&cursor[d.w], 1)] = s.w;
    } else {
        for (int k = i4; k < e; ++k) {
            int p = atomicAdd(&cursor[dst[k]], 1);
            csr_src[p] = src[k];
        }
    }
}

// 256-thread scan over n<=10240 (reads deg==cursor, writes row_start + cursor)
DEV_INLINE void scan_body(const int* __restrict__ deg, int* __restrict__ row_start,
                          int* __restrict__ cursor, int n) {
    __shared__ int sums[256];
    const int t = threadIdx.x;
    constexpr int ITEMS = 40;                  // 256*40 = 10240 >= n
    const int base = t * ITEMS;
    int local[ITEMS];
    int run = 0;
#pragma unroll
    for (int i = 0; i < ITEMS; ++i) {
        int idx = base + i;
        int v = (idx < n) ? deg[idx] : 0;
        local[i] = run;
        run += v;
    }
    sums[t] = run;
    __syncthreads();
    for (int off = 1; off < 256; off <<= 1) {
        int v = (t >= off) ? sums[t - off] : 0;
        __syncthreads();
        sums[t] += v;
        __syncthreads();
    }
    int prefix = (t == 0) ? 0 : sums[t - 1];
#pragma unroll
    for (int i = 0; i < ITEMS; ++i) {
        int idx = base + i;
        if (idx < n) {
            int v = prefix + local[i];
            row_start[idx] = v;
            cursor[idx] = v;
        }
    }
    if (t == 255) row_start[n] = sums[255];
}

// ---------------- MFMA GEMM body (cols >= NOUT routed to f32 als/ald) --------

DEV_INLINE int lds_slot(int r, int c) { return r * 4 + ((c + (r >> 1)) & 3); }

DEV_INLINE void gemm_body(const ushort_t* __restrict__ A, const ushort_t* __restrict__ BT,
                          ushort_t* __restrict__ C, float* __restrict__ ALS,
                          float* __restrict__ ALD, int M, int NOUT, int NH, int NTOT,
                          int K, int bx, int by) {
    __shared__ ushort_t As[64 * 32];
    __shared__ ushort_t Bs[64 * 32];
    const int tid = threadIdx.x;
    const int wave = tid >> 6, lane = tid & 63;
    const int row0 = by * 64;
    const int col0 = bx * 64;

    const int sr = tid >> 2, sc = tid & 3;
    const int a_row = row0 + sr;
    const int b_row = col0 + sr;

    const int fr = lane & 15;
    const int fc = lane >> 4;

    f32x4 acc0 = {}, acc1 = {}, acc2 = {}, acc3 = {};

    for (int k0 = 0; k0 < K; k0 += 32) {
        short8 av = {}, bv = {};
        if (a_row < M) av = *(const short8*)(A + (size_t)a_row * K + k0 + sc * 8);
        if (b_row < NTOT) bv = *(const short8*)(BT + (size_t)b_row * K + k0 + sc * 8);
        __syncthreads();
        *(short8*)(As + lds_slot(sr, sc) * 8) = av;
        *(short8*)(Bs + lds_slot(sr, sc) * 8) = bv;
        __syncthreads();

        const int arow = wave * 16 + fr;
        short8 afrag = *(const short8*)(As + lds_slot(arow, fc) * 8);
        short8 b0 = *(const short8*)(Bs + lds_slot(0 * 16 + fr, fc) * 8);
        short8 b1 = *(const short8*)(Bs + lds_slot(1 * 16 + fr, fc) * 8);
        short8 b2 = *(const short8*)(Bs + lds_slot(2 * 16 + fr, fc) * 8);
        short8 b3 = *(const short8*)(Bs + lds_slot(3 * 16 + fr, fc) * 8);
        acc0 = __builtin_amdgcn_mfma_f32_16x16x32_bf16(afrag, b0, acc0, 0, 0, 0);
        acc1 = __builtin_amdgcn_mfma_f32_16x16x32_bf16(afrag, b1, acc1, 0, 0, 0);
        acc2 = __builtin_amdgcn_mfma_f32_16x16x32_bf16(afrag, b2, acc2, 0, 0, 0);
        acc3 = __builtin_amdgcn_mfma_f32_16x16x32_bf16(afrag, b3, acc3, 0, 0, 0);
    }

    // C/D layout: col = lane&15, row = (lane>>4)*4 + reg
    const int crow = row0 + wave * 16 + (lane >> 4) * 4;
    const int ccol = col0 + (lane & 15);
    f32x4 accs[4] = {acc0, acc1, acc2, acc3};
#pragma unroll
    for (int ct = 0; ct < 4; ++ct) {
        int col = ccol + ct * 16;
#pragma unroll
        for (int j = 0; j < 4; ++j) {
            int row = crow + j;
            if (row >= M) continue;
            float v = accs[ct][j];
            if (col < NOUT) {
                C[(size_t)row * NOUT + col] = f2bf(v);
            } else {
                int cc = col - NOUT;
                if (cc < NH) ALS[(size_t)row * NH + cc] = v;
                else if (cc < 2 * NH) ALD[(size_t)row * NH + (cc - NH)] = v;
            }
        }
    }
}

__global__ __launch_bounds__(256) void gemm_kernel(const ushort_t* __restrict__ A,
                                                   const ushort_t* __restrict__ BT,
                                                   ushort_t* __restrict__ C,
                                                   float* __restrict__ ALS,
                                                   float* __restrict__ ALD,
                                                   int M, int NOUT, int NH, int NTOT,
                                                   int K, int gx) {
    gemm_body(A, BT, C, ALS, ALD, M, NOUT, NH, NTOT, K, blockIdx.x % gx, blockIdx.x / gx);
}

// block 0: CSR scan; blocks 1..: layer-1 GEMM
__global__ __launch_bounds__(256) void scan_gemm1_kernel(const int* __restrict__ deg,
                                                         int* __restrict__ row_start,
                                                         int* __restrict__ cursor, int n,
                                                         const ushort_t* __restrict__ A,
                                                         const ushort_t* __restrict__ BT,
                                                         ushort_t* __restrict__ C,
                                                         float* __restrict__ ALS,
                                                         float* __restrict__ ALD,
                                                         int M, int K, int gx) {
    if (blockIdx.x == 0) {
        scan_body(deg, row_start, cursor, n);
        return;
    }
    int b = blockIdx.x - 1;
    gemm_body(A, BT, C, ALS, ALD, M, 256, 8, 272, K, b % gx, b / gx);
}

// ---------------- aggregation, layers 1-2: 1 wave/node, 2 edges/step ---------
// Lanes 0-31 process even edges, lanes 32-63 odd edges; each lane owns 8
// channels (16B short8 gathers). Cross-half combine via shfl_xor(32).

__global__ __launch_bounds__(256) void aggregate_h8_kernel(const ushort_t* __restrict__ xp,
                                                           const float* __restrict__ als,
                                                           const float* __restrict__ ald,
                                                           const int* __restrict__ row_start,
                                                           const int* __restrict__ csr_src,
                                                           const float* __restrict__ bias,
                                                           ushort_t* __restrict__ out, int n) {
    int node = (blockIdx.x * blockDim.x + threadIdx.x) >> 6;
    int lane = threadIdx.x & 63;
    if (node >= n) return;
    const int half = lane >> 5;
    const int lh = lane & 31;
    const int ch = lh * 8;                 // 8 channels per lane
    const int head = lh >> 2;
    const int rs = row_start[node], re = row_start[node + 1];
    const float ad = ald[node * 8 + head];
    const float m = leaky02(als[node * 8 + head] + ad);   // shift = self-loop logit

    float acc[8];
    float ssum;
    if (half == 0) {                       // self loop counted once (half 0)
        short8 sv = *(const short8*)(xp + (size_t)node * 256 + ch);
#pragma unroll
        for (int i = 0; i < 8; ++i) acc[i] = bf2f((ushort_t)sv[i]);
        ssum = 1.0f;
    } else {
#pragma unroll
        for (int i = 0; i < 8; ++i) acc[i] = 0.f;
        ssum = 0.f;
    }

    for (int base = rs; base < re; base += 64) {
        const int cnt = (re - base < 64) ? (re - base) : 64;
        int myi = (lane < cnt) ? csr_src[base + lane] : 0;
        int j = 0;
        for (; j + 4 <= cnt; j += 4) {     // 4 edges: 2 per half, 2 loads in flight
            int sa = __shfl(myi, j + half);
            int sb = __shfl(myi, j + 2 + half);
            float aa = als[sa * 8 + head];
            float ab = als[sb * 8 + head];
            short8 va = *(const short8*)(xp + (size_t)sa * 256 + ch);
            short8 vb = *(const short8*)(xp + (size_t)sb * 256 + ch);
            float pa = __expf(leaky02(aa + ad) - m);
            float pb = __expf(leaky02(ab + ad) - m);
            ssum += pa + pb;
#pragma unroll
            for (int i = 0; i < 8; ++i)
                acc[i] += pa * bf2f((ushort_t)va[i]) + pb * bf2f((ushort_t)vb[i]);
        }
        for (; j < cnt; j += 2) {          // tail (cnt%4 != 0 => cnt < 64, jj <= 63)
            int jj = j + half;
            int s = __shfl(myi, jj);
            bool valid = jj < cnt;
            float a = als[s * 8 + head];
            short8 v = *(const short8*)(xp + (size_t)s * 256 + ch);
            float p = valid ? __expf(leaky02(a + ad) - m) : 0.f;
            ssum += p;
#pragma unroll
            for (int i = 0; i < 8; ++i) acc[i] += p * bf2f((ushort_t)v[i]);
        }
    }

    ssum += __shfl_xor(ssum, 32);
#pragma unroll
    for (int i = 0; i < 8; ++i) acc[i] += __shfl_xor(acc[i], 32);

    if (half == 0) {
        float inv = 1.f / ssum;
        float4 ba = *(const float4*)(bias + ch);
        float4 bb = *(const float4*)(bias + ch + 4);
        float bv[8] = {ba.x, ba.y, ba.z, ba.w, bb.x, bb.y, bb.z, bb.w};
        short8 o;
#pragma unroll
        for (int i = 0; i < 8; ++i) o[i] = (short)f2bf(elu1(acc[i] * inv + bv[i]));
        *(short8*)(out + (size_t)node * 256 + ch) = o;
    }
}

// ---------------- aggregation layer 3 (H=1, C=40) + bias + log_softmax -------
// Same two-edge split; 20 active lanes per half, ushort2 (2 ch) per lane.

__global__ __launch_bounds__(256) void aggregate_out_kernel(const ushort_t* __restrict__ xp,
                                                            const float* __restrict__ als,
                                                            const float* __restrict__ ald,
                                                            const int* __restrict__ row_start,
                                                            const int* __restrict__ csr_src,
                                                            const float* __restrict__ bias,
                                                            float* __restrict__ out, int n) {
    int node = (blockIdx.x * blockDim.x + threadIdx.x) >> 6;
    int lane = threadIdx.x & 63;
    if (node >= n) return;
    const int half = lane >> 5;
    const int lh = lane & 31;
    const bool act = lh < 20;
    const int ch = lh * 2;
    const int rs = row_start[node], re = row_start[node + 1];
    const float ad = ald[node];
    const float m = leaky02(als[node] + ad);

    float a0, a1, ssum;
    if (half == 0) {
        if (act) {
            ushort2 sv = *(const ushort2*)(xp + (size_t)node * 40 + ch);
            a0 = bf2f(sv.x); a1 = bf2f(sv.y);
        } else { a0 = a1 = 0.f; }
        ssum = 1.0f;
    } else { a0 = a1 = 0.f; ssum = 0.f; }

    for (int base = rs; base < re; base += 64) {
        const int cnt = (re - base < 64) ? (re - base) : 64;
        int myi = (lane < cnt) ? csr_src[base + lane] : 0;
        int j = 0;
        for (; j + 4 <= cnt; j += 4) {
            int sa = __shfl(myi, j + half);
            int sb = __shfl(myi, j + 2 + half);
            float aa = als[sa];
            float ab = als[sb];
            ushort2 va = act ? *(const ushort2*)(xp + (size_t)sa * 40 + ch) : ushort2{0, 0};
            ushort2 vb = act ? *(const ushort2*)(xp + (size_t)sb * 40 + ch) : ushort2{0, 0};
            float pa = __expf(leaky02(aa + ad) - m);
            float pb = __expf(leaky02(ab + ad) - m);
            ssum += pa + pb;
            a0 += pa * bf2f(va.x) + pb * bf2f(vb.x);
            a1 += pa * bf2f(va.y) + pb * bf2f(vb.y);
        }
        for (; j < cnt; j += 2) {
            int jj = j + half;
            int s = __shfl(myi, jj);
            bool valid = jj < cnt;
            float a = als[s];
            ushort2 v = act ? *(const ushort2*)(xp + (size_t)s * 40 + ch) : ushort2{0, 0};
            float p = valid ? __expf(leaky02(a + ad) - m) : 0.f;
            ssum += p;
            a0 += p * bf2f(v.x);
            a1 += p * bf2f(v.y);
        }
    }

    ssum += __shfl_xor(ssum, 32);
    a0 += __shfl_xor(a0, 32);
    a1 += __shfl_xor(a1, 32);

    float inv = 1.f / ssum;
    float2 b2 = act ? *(const float2*)(bias + ch) : float2{0.f, 0.f};
    float o0 = act ? (a0 * inv + b2.x) : -INFINITY;
    float o1 = act ? (a1 * inv + b2.y) : -INFINITY;

    // log_softmax over 40 channels held by lanes 0..19 of each half (reduce within 32)
    float mx = fmaxf(o0, o1);
#pragma unroll
    for (int off = 16; off >= 1; off >>= 1) mx = fmaxf(mx, __shfl_xor(mx, off));
    float ex = act ? (__expf(o0 - mx) + __expf(o1 - mx)) : 0.f;
#pragma unroll
    for (int off = 16; off >= 1; off >>= 1) ex += __shfl_xor(ex, off);
    float lse = mx + __logf(ex);
    if (half == 0 && act) {
        float2 o = {o0 - lse, o1 - lse};
        *(float2*)(out + (size_t)node * 40 + ch) = o;
    }
}

// ---------------------------------------------------------------------------

extern "C" void kernel_launch(void* const* d_in, const int* in_sizes, int n_in,
                              void* d_out, int out_size, void* d_ws, size_t ws_size,
                              hipStream_t stream) {
    const float* x      = (const float*)d_in[0];
    const int*   edge   = (const int*)d_in[1];
    const float* W1     = (const float*)d_in[2];
    const float* a_src1 = (const float*)d_in[3];
    const float* a_dst1 = (const float*)d_in[4];
    const float* b1     = (const float*)d_in[5];
    const float* W2     = (const float*)d_in[6];
    const float* a_src2 = (const float*)d_in[7];
    const float* a_dst2 = (const float*)d_in[8];
    const float* b2     = (const float*)d_in[9];
    const float* W3     = (const float*)d_in[10];
    const float* a_src3 = (const float*)d_in[11];
    const float* a_dst3 = (const float*)d_in[12];
    const float* b3     = (const float*)d_in[13];
    float* out = (float*)d_out;

    const int n = in_sizes[0] / 128;   // 10000
    const int e = in_sizes[1] / 2;     // 320000

    char* ws = (char*)d_ws;
    size_t off = 0;
    auto alloc = [&](size_t bytes) -> void* {
        void* p = ws + off;
        off += (bytes + 255) & ~(size_t)255;
        return p;
    };
    ushort_t* xp        = (ushort_t*)alloc((size_t)n * 256 * 2);
    ushort_t* h_bf      = (ushort_t*)alloc((size_t)n * 256 * 2);
    ushort_t* xp3       = (ushort_t*)alloc((size_t)n * 40 * 2);
    ushort_t* x_bf      = (ushort_t*)alloc((size_t)n * 128 * 2);
    ushort_t* W1T       = (ushort_t*)alloc((size_t)272 * 128 * 2);
    ushort_t* W2T       = (ushort_t*)alloc((size_t)272 * 256 * 2);
    ushort_t* W3T       = (ushort_t*)alloc((size_t)42 * 256 * 2);
    float*    als       = (float*)alloc((size_t)n * 8 * 4);
    float*    ald       = (float*)alloc((size_t)n * 8 * 4);
    int*      row_start = (int*)alloc((size_t)(n + 1) * 4);
    int*      cursor    = (int*)alloc((size_t)n * 4);
    int*      csr_src   = (int*)alloc((size_t)e * 4);
    (void)ws_size;

    const int* srcs = edge;
    const int* dsts = edge + e;

    const int mby = (n + 63) / 64;             // 157
    const int e4blocks = ((e + 3) / 4 + 255) / 256;

    // K0: zero cursor
    hipMemsetAsync(cursor, 0, (size_t)n * 4, stream);
    // K1: degree count (blocks [0,e4blocks)) || prep (rest)
    {
        int prep_total = n * 32 + 128 * 256 + 256 * 256 + 256 * 40
                       + 1024 + 1024 + 2048 + 2048 + 256 + 256;
        int prepBlocks = (prep_total + 255) / 256;
        prep_count_kernel<<<e4blocks + prepBlocks, 256, 0, stream>>>(
            x, x_bf, W1, W1T, W2, W2T, W3, W3T,
            a_src1, a_dst1, a_src2, a_dst2, a_src3, a_dst3,
            dsts, cursor, e, e4blocks, n);
    }
    // K2: scan (block 0) || layer-1 GEMM (blocks 1..)
    scan_gemm1_kernel<<<1 + 5 * mby, 256, 0, stream>>>(cursor, row_start, cursor, n,
                                                       x_bf, W1T, xp, als, ald, n, 128, 5);
    // K3: CSR scatter
    scatter_csr_kernel<<<e4blocks, 256, 0, stream>>>(srcs, dsts, cursor, csr_src, e);

    const int agg_grid = (n * 64 + 255) / 256;

    // K4: layer-1 aggregation (+bias+ELU) -> h_bf
    aggregate_h8_kernel<<<agg_grid, 256, 0, stream>>>(xp, als, ald, row_start, csr_src, b1, h_bf, n);
    // K5: layer-2 GEMM (+al fold)
    gemm_kernel<<<5 * mby, 256, 0, stream>>>(h_bf, W2T, xp, als, ald, n, 256, 8, 272, 256, 5);
    // K6: layer-2 aggregation -> h_bf
    aggregate_h8_kernel<<<agg_grid, 256, 0, stream>>>(xp, als, ald, row_start, csr_src, b2, h_bf, n);
    // K7: layer-3 GEMM (+al fold)
    gemm_kernel<<<1 * mby, 256, 0, stream>>>(h_bf, W3T, xp3, als, ald, n, 40, 1, 42, 256, 1);
    // K8: layer-3 aggregation + bias + log_softmax
    aggregate_out_kernel<<<agg_grid, 256, 0, stream>>>(xp3, als, ald, row_start, csr_src, b3, out, n);
}